// Round 5
// baseline (1581.924 us; speedup 1.0000x reference)
//
#include <hip/hip_runtime.h>
#include <hip/hip_bf16.h>
#include <cstdint>
#include <cstddef>

typedef __attribute__((ext_vector_type(8))) short bf16x8;
typedef __attribute__((ext_vector_type(4))) float f32x4;

__device__ inline float bf2f(unsigned short u) {
    union { float f; unsigned int i; } c; c.i = ((unsigned int)u) << 16; return c.f;
}
__device__ inline unsigned short f2b(float v) {
    __hip_bfloat16 h = __float2bfloat16(v);
    union { __hip_bfloat16 b; unsigned short u; } c; c.b = h; return c.u;
}

__device__ inline float wmax64(float v) {
    #pragma unroll
    for (int o = 32; o; o >>= 1) v = fmaxf(v, __shfl_xor(v, o));
    return v;
}
__device__ inline float wsum64(float v) {
    #pragma unroll
    for (int o = 32; o; o >>= 1) v += __shfl_xor(v, o);
    return v;
}

// ---------------- CSR / bucket-sort construction ----------------
__global__ void k_count(const int* __restrict__ dst, int* __restrict__ indeg, int E_) {
    int e = blockIdx.x * 256 + threadIdx.x;
    if (e < E_) atomicAdd(&indeg[dst[e]], 1);
}

__global__ __launch_bounds__(1024) void k_scan(const int* __restrict__ indeg, int* __restrict__ coff, int nn) {
    __shared__ int part[1024];
    const int t = threadIdx.x;
    const int CH = (nn + 1023) >> 10;
    int loc[16];
    int s = 0;
    #pragma unroll
    for (int j = 0; j < 16; ++j) {
        if (j < CH) {
            int idx = t * CH + j;
            loc[j] = s;
            s += (idx < nn) ? indeg[idx] : 0;
        }
    }
    part[t] = s;
    __syncthreads();
    for (int o = 1; o < 1024; o <<= 1) {
        int v = (t >= o) ? part[t - o] : 0;
        __syncthreads();
        part[t] += v;
        __syncthreads();
    }
    const int base = (t > 0) ? part[t - 1] : 0;
    #pragma unroll
    for (int j = 0; j < 16; ++j) {
        if (j < CH) {
            int idx = t * CH + j;
            if (idx < nn) coff[idx] = base + loc[j];
        }
    }
    if (t == 1023) coff[nn] = part[1023];
}

__global__ void k_fill(const int* __restrict__ dst, const int* __restrict__ coff,
                       int* __restrict__ fill, int* __restrict__ ceid, int E_) {
    int e = blockIdx.x * 256 + threadIdx.x;
    if (e < E_) {
        int d = dst[e];
        int p = atomicAdd(&fill[d], 1);
        ceid[coff[d] + p] = e;
    }
}

// ---------------- misc small kernels ----------------
__global__ void k_copy_x(const float* __restrict__ x, float* __restrict__ feat, int nn) {
    int t = blockIdx.x * 256 + threadIdx.x;
    if (t < nn * 39) feat[(size_t)(t / 39) * 551 + (t % 39)] = x[t];
}

__global__ __launch_bounds__(128) void k_loopattr(const float* __restrict__ ea, const int* __restrict__ coff,
                                                  const int* __restrict__ ceid, float* __restrict__ la, int nn) {
    int g = blockIdx.x * 4 + (threadIdx.x >> 5);
    int lane = threadIdx.x & 31;
    if (g >= nn || lane >= 27) return;
    int beg = coff[g], cnt = coff[g + 1] - beg;
    float v = 0.f;
    for (int e = 0; e < cnt; ++e) v += ea[(size_t)ceid[beg + e] * 27 + lane];
    la[(size_t)g * 27 + lane] = v / fmaxf((float)cnt, 1.f);
}

__global__ void k_wea(const float* __restrict__ We, const float* __restrict__ aedge, float* __restrict__ Wea) {
    int t = threadIdx.x;
    if (t >= 108) return;
    int f = t >> 2, hh = t & 3;
    float v = 0.f;
    for (int d = 0; d < 128; ++d) v += We[(size_t)f * 512 + hh * 128 + d] * aedge[hh * 128 + d];
    Wea[f * 4 + hh] = v;
}

__global__ void k_ae(const float* __restrict__ ea, const float* __restrict__ la,
                     const float* __restrict__ Wea, float* __restrict__ a_e, int E_, int nn) {
    int r = blockIdx.x * 256 + threadIdx.x;
    if (r >= E_ + nn) return;
    const float* src = (r < E_) ? (ea + (size_t)r * 27) : (la + (size_t)(r - E_) * 27);
    float o0 = 0, o1 = 0, o2 = 0, o3 = 0;
    #pragma unroll
    for (int f = 0; f < 27; ++f) {
        float xv = src[f];
        o0 += xv * Wea[f * 4 + 0];
        o1 += xv * Wea[f * 4 + 1];
        o2 += xv * Wea[f * 4 + 2];
        o3 += xv * Wea[f * 4 + 3];
    }
    a_e[(size_t)r * 4 + 0] = o0; a_e[(size_t)r * 4 + 1] = o1;
    a_e[(size_t)r * 4 + 2] = o2; a_e[(size_t)r * 4 + 3] = o3;
}

__global__ void k_asd(const float* __restrict__ h, const float* __restrict__ asrc,
                      const float* __restrict__ adst, float* __restrict__ a_s,
                      float* __restrict__ a_d, int nn) {
    int t = blockIdx.x * 256 + threadIdx.x;
    if (t >= nn * 4) return;
    int node = t >> 2, hh = t & 3;
    const float* hp = h + (size_t)node * 512 + hh * 128;
    float vs = 0.f, vd = 0.f;
    for (int d = 0; d < 128; ++d) {
        float xv = hp[d];
        vs += xv * asrc[hh * 128 + d];
        vd += xv * adst[hh * 128 + d];
    }
    a_s[t] = vs;
    a_d[t] = vd;
}

// ---------------- GAT attention + aggregation (per node, 1 wave) ----------------
__global__ __launch_bounds__(64) void k_attn(
    const float* __restrict__ h, const float* __restrict__ a_s, const float* __restrict__ a_d,
    const float* __restrict__ a_e, const int* __restrict__ esrc,
    const int* __restrict__ coff, const int* __restrict__ ceid,
    const float* __restrict__ bvec, float* __restrict__ feat, int colofs, int E_) {
    const int i = blockIdx.x;
    const int lane = threadIdx.x;
    const int beg = coff[i];
    const int cnt = coff[i + 1] - beg;
    const int total = cnt + 1;
    const float d0 = a_d[i * 4 + 0], d1 = a_d[i * 4 + 1], d2 = a_d[i * 4 + 2], d3 = a_d[i * 4 + 3];
    float m0 = -1e30f, m1 = -1e30f, m2 = -1e30f, m3 = -1e30f;
    for (int e = lane; e < total; e += 64) {
        int eid, s;
        if (e < cnt) { eid = ceid[beg + e]; s = esrc[eid]; } else { eid = E_ + i; s = i; }
        float l0 = a_s[s * 4 + 0] + d0 + a_e[(size_t)eid * 4 + 0];
        float l1 = a_s[s * 4 + 1] + d1 + a_e[(size_t)eid * 4 + 1];
        float l2 = a_s[s * 4 + 2] + d2 + a_e[(size_t)eid * 4 + 2];
        float l3 = a_s[s * 4 + 3] + d3 + a_e[(size_t)eid * 4 + 3];
        l0 = l0 > 0.f ? l0 : 0.2f * l0;
        l1 = l1 > 0.f ? l1 : 0.2f * l1;
        l2 = l2 > 0.f ? l2 : 0.2f * l2;
        l3 = l3 > 0.f ? l3 : 0.2f * l3;
        m0 = fmaxf(m0, l0); m1 = fmaxf(m1, l1); m2 = fmaxf(m2, l2); m3 = fmaxf(m3, l3);
    }
    m0 = wmax64(m0); m1 = wmax64(m1); m2 = wmax64(m2); m3 = wmax64(m3);
    float s0 = 0, s1 = 0, s2 = 0, s3 = 0;
    for (int e = lane; e < total; e += 64) {
        int eid, s;
        if (e < cnt) { eid = ceid[beg + e]; s = esrc[eid]; } else { eid = E_ + i; s = i; }
        float l0 = a_s[s * 4 + 0] + d0 + a_e[(size_t)eid * 4 + 0];
        float l1 = a_s[s * 4 + 1] + d1 + a_e[(size_t)eid * 4 + 1];
        float l2 = a_s[s * 4 + 2] + d2 + a_e[(size_t)eid * 4 + 2];
        float l3 = a_s[s * 4 + 3] + d3 + a_e[(size_t)eid * 4 + 3];
        l0 = l0 > 0.f ? l0 : 0.2f * l0;
        l1 = l1 > 0.f ? l1 : 0.2f * l1;
        l2 = l2 > 0.f ? l2 : 0.2f * l2;
        l3 = l3 > 0.f ? l3 : 0.2f * l3;
        s0 += __expf(l0 - m0); s1 += __expf(l1 - m1);
        s2 += __expf(l2 - m2); s3 += __expf(l3 - m3);
    }
    s0 = wsum64(s0); s1 = wsum64(s1); s2 = wsum64(s2); s3 = wsum64(s3);
    const int myh = lane >> 4;
    const float mm = myh == 0 ? m0 : myh == 1 ? m1 : myh == 2 ? m2 : m3;
    const float sv = myh == 0 ? s0 : myh == 1 ? s1 : myh == 2 ? s2 : s3;
    const float dd = myh == 0 ? d0 : myh == 1 ? d1 : myh == 2 ? d2 : d3;
    const float iv = 1.f / (sv + 1e-16f);
    float acc[8] = {0, 0, 0, 0, 0, 0, 0, 0};
    for (int e = 0; e < total; ++e) {
        int eid, s;
        if (e < cnt) { eid = ceid[beg + e]; s = esrc[eid]; } else { eid = E_ + i; s = i; }
        float l = a_s[s * 4 + myh] + dd + a_e[(size_t)eid * 4 + myh];
        l = l > 0.f ? l : 0.2f * l;
        const float wgt = __expf(l - mm) * iv;
        const float4* hp = (const float4*)(h + (size_t)s * 512 + lane * 8);
        float4 x0 = hp[0], x1 = hp[1];
        acc[0] += wgt * x0.x; acc[1] += wgt * x0.y; acc[2] += wgt * x0.z; acc[3] += wgt * x0.w;
        acc[4] += wgt * x1.x; acc[5] += wgt * x1.y; acc[6] += wgt * x1.z; acc[7] += wgt * x1.w;
    }
    __shared__ float sh[512];
    #pragma unroll
    for (int j = 0; j < 8; ++j) sh[lane * 8 + j] = acc[j];
    __syncthreads();
    #pragma unroll
    for (int r = 0; r < 2; ++r) {
        int d = lane * 2 + r;
        float v = 0.25f * (sh[d] + sh[128 + d] + sh[256 + d] + sh[384 + d]) + bvec[d];
        feat[(size_t)i * 551 + colofs + d] = fmaxf(v, 0.f);
    }
}

// ---------------- GCN aggregation ----------------
__global__ __launch_bounds__(64) void k_gcn(const float* __restrict__ hg, const int* __restrict__ esrc,
    const int* __restrict__ coff, const int* __restrict__ ceid, const int* __restrict__ indeg,
    const float* __restrict__ bvec, float* __restrict__ feat) {
    const int i = blockIdx.x;
    const int lane = threadIdx.x;
    const int beg = coff[i];
    const int cnt = coff[i + 1] - beg;
    const float di = rsqrtf((float)(indeg[i] + 1));
    const int d = lane * 2;
    float acc0 = hg[(size_t)i * 128 + d] * di;
    float acc1 = hg[(size_t)i * 128 + d + 1] * di;
    for (int e = 0; e < cnt; ++e) {
        int eid = ceid[beg + e];
        int s = esrc[eid];
        float ds = rsqrtf((float)(indeg[s] + 1));
        acc0 += hg[(size_t)s * 128 + d] * ds;
        acc1 += hg[(size_t)s * 128 + d + 1] * ds;
    }
    feat[(size_t)i * 551 + 423 + d] = acc0 * di + bvec[d];
    feat[(size_t)i * 551 + 423 + d + 1] = acc1 * di + bvec[d + 1];
}

// ---------------- pair features ----------------
__global__ void k_pair(const int* __restrict__ idx, const float* __restrict__ xyz,
                       const float* __restrict__ vec, float* __restrict__ dv,
                       float* __restrict__ av, int P) {
    int p = blockIdx.x * 256 + threadIdx.x;
    if (p >= P) return;
    int i = idx[p], j = idx[P + p];
    float dx = xyz[i * 3] - xyz[j * 3];
    float dy = xyz[i * 3 + 1] - xyz[j * 3 + 1];
    float dz = xyz[i * 3 + 2] - xyz[j * 3 + 2];
    dv[p] = dx * dx + dy * dy + dz * dz;
    float a0 = vec[i * 3], a1 = vec[i * 3 + 1], a2 = vec[i * 3 + 2];
    float b0 = vec[j * 3], b1 = vec[j * 3 + 1], b2 = vec[j * 3 + 2];
    float na = fmaxf(sqrtf(a0 * a0 + a1 * a1 + a2 * a2), 1e-8f);
    float nb = fmaxf(sqrtf(b0 * b0 + b1 * b1 + b2 * b2), 1e-8f);
    av[p] = (a0 * b0 + a1 * b1 + a2 * b2) / (na * nb);
}

// ---------------- bf16 staging ----------------
__global__ void k_stage_a(const float* __restrict__ src, int lds, int off,
                          unsigned short* __restrict__ dst, int ldd, int M, int K, int Mp) {
    int idx = blockIdx.x * 256 + threadIdx.x;
    if (idx >= Mp * ldd) return;
    int m = idx / ldd, k = idx - m * ldd;
    float v = (m < M && k < K) ? src[(size_t)m * lds + off + k] : 0.f;
    dst[idx] = f2b(v);
}

__global__ void k_conv_bt(const float* __restrict__ src, int ldn,
                          unsigned short* __restrict__ dst, int Kp, int K, int N, int Np) {
    int idx = blockIdx.x * 256 + threadIdx.x;
    if (idx >= Np * Kp) return;
    int nrow = idx / Kp, k = idx - nrow * Kp;
    float v = (nrow < N && k < K) ? src[(size_t)k * ldn + nrow] : 0.f;
    dst[idx] = f2b(v);
}

// ---------------- MFMA bf16 NT-GEMM ----------------
template<int OUT, bool RELU, bool BIAS>
__global__ __launch_bounds__(256) void gemm_mfma(
    const unsigned short* __restrict__ A, int lda,
    const unsigned short* __restrict__ Bt, int ldb,
    const float* __restrict__ bias,
    void* __restrict__ Cv, int ldc,
    int M, int N, int K) {
    const int t = threadIdx.x;
    const int lane = t & 63;
    const int wid = t >> 6;
    const int wm = wid >> 1, wn = wid & 1;
    const int bm0 = blockIdx.y * 128 + wm * 64;
    const int bn0 = blockIdx.x * 128 + wn * 64;
    const int r = lane & 15, g = lane >> 4;
    f32x4 acc[4][4] = {};
    const unsigned short* Ap = A + (size_t)(bm0 + r) * lda + 8 * g;
    const unsigned short* Bp = Bt + (size_t)(bn0 + r) * ldb + 8 * g;
    for (int k0 = 0; k0 < K; k0 += 32) {
        bf16x8 a[4], b[4];
        #pragma unroll
        for (int i = 0; i < 4; ++i) {
            a[i] = *(const bf16x8*)(Ap + (size_t)(i * 16) * lda + k0);
            b[i] = *(const bf16x8*)(Bp + (size_t)(i * 16) * ldb + k0);
        }
        #pragma unroll
        for (int i = 0; i < 4; ++i)
            #pragma unroll
            for (int j = 0; j < 4; ++j)
                acc[i][j] = __builtin_amdgcn_mfma_f32_16x16x32_bf16(a[i], b[j], acc[i][j], 0, 0, 0);
    }
    #pragma unroll
    for (int i = 0; i < 4; ++i) {
        #pragma unroll
        for (int reg = 0; reg < 4; ++reg) {
            const int row = bm0 + i * 16 + 4 * g + reg;
            if (row >= M) continue;
            #pragma unroll
            for (int j = 0; j < 4; ++j) {
                const int col = bn0 + j * 16 + r;
                if (col >= N) continue;
                float v = acc[i][j][reg];
                if constexpr (BIAS) v += bias[col];
                if constexpr (RELU) v = fmaxf(v, 0.f);
                if constexpr (OUT == 0) ((float*)Cv)[(size_t)row * ldc + col] = v;
                else ((unsigned short*)Cv)[(size_t)row * ldc + col] = f2b(v);
            }
        }
    }
}

// ---------------- column stats over bf16 hidden [M,1024] ----------------
__global__ __launch_bounds__(256) void k_stats1b(const unsigned short* __restrict__ Hm, int M, float* __restrict__ part) {
    const int b = blockIdx.x, t = threadIdx.x;
    const int chunk = (M + 255) / 256;
    const int r0 = b * chunk;
    const int r1 = min(M, r0 + chunk);
    float s[4] = {0, 0, 0, 0}, ss[4] = {0, 0, 0, 0};
    for (int r = r0; r < r1; ++r) {
        const ushort4 q = *(const ushort4*)(Hm + (size_t)r * 1024 + t * 4);
        float v0 = bf2f(q.x), v1 = bf2f(q.y), v2 = bf2f(q.z), v3 = bf2f(q.w);
        s[0] += v0; ss[0] += v0 * v0;
        s[1] += v1; ss[1] += v1 * v1;
        s[2] += v2; ss[2] += v2 * v2;
        s[3] += v3; ss[3] += v3 * v3;
    }
    #pragma unroll
    for (int j = 0; j < 4; ++j) {
        part[(size_t)b * 2048 + t * 4 + j] = s[j];
        part[(size_t)b * 2048 + 1024 + t * 4 + j] = ss[j];
    }
}

// ---------------- two-stage parallel column reduce ----------------
__global__ __launch_bounds__(256) void k_red1(const float* __restrict__ part, float* __restrict__ tmp,
                                              int NB, int nch) {
    const int c = blockIdx.x * 256 + threadIdx.x;
    const int ch = blockIdx.y;
    const int per = (NB + nch - 1) / nch;
    const int b0 = ch * per;
    const int b1 = min(NB, b0 + per);
    float s = 0.f;
    for (int b = b0; b < b1; ++b) s += part[(size_t)b * 2048 + c];
    tmp[(size_t)ch * 2048 + c] = s;
}
__global__ void k_red2(const float* __restrict__ tmp, float* __restrict__ mv, int M, int nch) {
    int c = blockIdx.x * 256 + threadIdx.x;
    if (c >= 1024) return;
    float s = 0.f, ss = 0.f;
    for (int ch = 0; ch < nch; ++ch) {
        s += tmp[(size_t)ch * 2048 + c];
        ss += tmp[(size_t)ch * 2048 + 1024 + c];
    }
    float m = s / (float)M;
    float v = ss / (float)M - m * m;
    mv[c] = m;
    mv[1024 + c] = fmaxf(v, 0.f);
}

// ---------------- fold BN into W2 ----------------
__global__ __launch_bounds__(256) void k_fold(const float* __restrict__ W2, const float* __restrict__ g,
    const float* __restrict__ be, const float* __restrict__ b2, const float* __restrict__ mv,
    float* __restrict__ W2f, float* __restrict__ b2f, int NO) {
    const int c = blockIdx.x;
    const int t = threadIdx.x;
    __shared__ float red[256];
    float accb = 0.f;
    for (int k = t; k < 1024; k += 256) {
        float s = (1.f / sqrtf(mv[1024 + k] + 1e-5f)) * g[k];
        float wv = W2[(size_t)k * NO + c];
        W2f[(size_t)k * NO + c] = wv * s;
        accb += (be[k] - mv[k] * s) * wv;
    }
    red[t] = accb;
    __syncthreads();
    for (int o = 128; o; o >>= 1) {
        if (t < o) red[t] += red[t + o];
        __syncthreads();
    }
    if (t == 0) b2f[c] = b2[c] + red[0];
}

// ---------------- pair-head pass A (sorted order, 2x unroll) ----------------
template<bool HASEX>
__global__ __launch_bounds__(256) void k_pairA(
    const unsigned short* __restrict__ u0, const unsigned short* __restrict__ u1,
    const float* __restrict__ b1, const float* __restrict__ W1ex,
    const int* __restrict__ idx, const int* __restrict__ sid,
    const float* __restrict__ dv, const float* __restrict__ av,
    int P, float* __restrict__ part) {
    const int b = blockIdx.x, t = threadIdx.x;
    const int chunk = (P + 1023) / 1024;
    const int r0 = b * chunk;
    const int r1 = min(P, r0 + chunk);
    const float4 bb = *(const float4*)(b1 + t * 4);
    float4 wd = make_float4(0, 0, 0, 0), wa = make_float4(0, 0, 0, 0);
    if constexpr (HASEX) {
        wd = *(const float4*)(W1ex + t * 4);
        wa = *(const float4*)(W1ex + 1024 + t * 4);
    }
    float s[4] = {0, 0, 0, 0}, ss[4] = {0, 0, 0, 0};
    int r = r0;
    for (; r + 1 < r1; r += 2) {
        const int pA = sid[r], pB = sid[r + 1];
        const int i0A = idx[pA], i1A = idx[P + pA];
        const int i0B = idx[pB], i1B = idx[P + pB];
        const ushort4 q0A = *(const ushort4*)(u0 + (size_t)i0A * 1024 + t * 4);
        const ushort4 q1A = *(const ushort4*)(u1 + (size_t)i1A * 1024 + t * 4);
        const ushort4 q0B = *(const ushort4*)(u0 + (size_t)i0B * 1024 + t * 4);
        const ushort4 q1B = *(const ushort4*)(u1 + (size_t)i1B * 1024 + t * 4);
        float hA[4], hB[4];
        hA[0] = bf2f(q0A.x) + bf2f(q1A.x) + bb.x;
        hA[1] = bf2f(q0A.y) + bf2f(q1A.y) + bb.y;
        hA[2] = bf2f(q0A.z) + bf2f(q1A.z) + bb.z;
        hA[3] = bf2f(q0A.w) + bf2f(q1A.w) + bb.w;
        hB[0] = bf2f(q0B.x) + bf2f(q1B.x) + bb.x;
        hB[1] = bf2f(q0B.y) + bf2f(q1B.y) + bb.y;
        hB[2] = bf2f(q0B.z) + bf2f(q1B.z) + bb.z;
        hB[3] = bf2f(q0B.w) + bf2f(q1B.w) + bb.w;
        if constexpr (HASEX) {
            const float dA = dv[pA], aA = av[pA];
            const float dB = dv[pB], aB = av[pB];
            hA[0] += dA * wd.x + aA * wa.x; hA[1] += dA * wd.y + aA * wa.y;
            hA[2] += dA * wd.z + aA * wa.z; hA[3] += dA * wd.w + aA * wa.w;
            hB[0] += dB * wd.x + aB * wa.x; hB[1] += dB * wd.y + aB * wa.y;
            hB[2] += dB * wd.z + aB * wa.z; hB[3] += dB * wd.w + aB * wa.w;
        }
        #pragma unroll
        for (int j = 0; j < 4; ++j) {
            float hvA = fmaxf(hA[j], 0.f);
            float hvB = fmaxf(hB[j], 0.f);
            s[j] += hvA + hvB; ss[j] += hvA * hvA + hvB * hvB;
        }
    }
    if (r < r1) {
        const int p = sid[r];
        const int i0 = idx[p], i1 = idx[P + p];
        const ushort4 q0 = *(const ushort4*)(u0 + (size_t)i0 * 1024 + t * 4);
        const ushort4 q1 = *(const ushort4*)(u1 + (size_t)i1 * 1024 + t * 4);
        float h[4];
        h[0] = bf2f(q0.x) + bf2f(q1.x) + bb.x;
        h[1] = bf2f(q0.y) + bf2f(q1.y) + bb.y;
        h[2] = bf2f(q0.z) + bf2f(q1.z) + bb.z;
        h[3] = bf2f(q0.w) + bf2f(q1.w) + bb.w;
        if constexpr (HASEX) {
            const float d = dv[p], a = av[p];
            h[0] += d * wd.x + a * wa.x; h[1] += d * wd.y + a * wa.y;
            h[2] += d * wd.z + a * wa.z; h[3] += d * wd.w + a * wa.w;
        }
        #pragma unroll
        for (int j = 0; j < 4; ++j) {
            float hv = fmaxf(h[j], 0.f);
            s[j] += hv; ss[j] += hv * hv;
        }
    }
    #pragma unroll
    for (int j = 0; j < 4; ++j) {
        part[(size_t)b * 2048 + t * 4 + j] = s[j];
        part[(size_t)b * 2048 + 1024 + t * 4 + j] = ss[j];
    }
}

// ---------------- pair-head pass B (sorted order, wave per pair) ----------------
template<int NO, bool HASEX>
__global__ __launch_bounds__(256) void k_pairB(
    const unsigned short* __restrict__ u0, const unsigned short* __restrict__ u1,
    const float* __restrict__ b1, const float* __restrict__ W1ex,
    const float* __restrict__ W2f, const float* __restrict__ b2f,
    const int* __restrict__ idx, const int* __restrict__ sid,
    const float* __restrict__ dv, const float* __restrict__ av,
    float* __restrict__ out, int P) {
    const int t = threadIdx.x;
    const int wid = t >> 6, lane = t & 63;
    const int srow = blockIdx.x * 4 + wid;
    if (srow >= P) return;
    const int row = sid[srow];
    const int i0 = idx[row], i1 = idx[P + row];
    const int k0 = lane * 16;
    float d = 0.f, a = 0.f;
    if constexpr (HASEX) { d = dv[row]; a = av[row]; }
    float acc[NO];
    #pragma unroll
    for (int no = 0; no < NO; ++no) acc[no] = 0.f;
    const unsigned short* p0 = u0 + (size_t)i0 * 1024 + k0;
    const unsigned short* p1 = u1 + (size_t)i1 * 1024 + k0;
    union { uint4 u; unsigned short us[8]; } qa0, qa1, qb0, qb1;
    qa0.u = *(const uint4*)(p0);
    qa1.u = *(const uint4*)(p0 + 8);
    qb0.u = *(const uint4*)(p1);
    qb1.u = *(const uint4*)(p1 + 8);
    #pragma unroll
    for (int j = 0; j < 16; ++j) {
        const int kk = k0 + j;
        float h = (j < 8 ? bf2f(qa0.us[j]) : bf2f(qa1.us[j - 8]))
                + (j < 8 ? bf2f(qb0.us[j]) : bf2f(qb1.us[j - 8]))
                + b1[kk];
        if constexpr (HASEX) h += d * W1ex[kk] + a * W1ex[1024 + kk];
        const float hv = fmaxf(h, 0.f);
        #pragma unroll
        for (int no = 0; no < NO; ++no) acc[no] += hv * W2f[(size_t)kk * NO + no];
    }
    #pragma unroll
    for (int no = 0; no < NO; ++no) {
        float v = acc[no];
        #pragma unroll
        for (int o = 32; o; o >>= 1) v += __shfl_down(v, o);
        if (lane == 0) out[(size_t)row * NO + no] = v + b2f[no];
    }
}

// ---------------- host driver ----------------
extern "C" void kernel_launch(void* const* d_in, const int* in_sizes, int n_in,
                              void* d_out, int out_size, void* d_ws, size_t ws_size,
                              hipStream_t stream) {
    (void)n_in; (void)out_size; (void)ws_size;
    const float* x     = (const float*)d_in[0];
    const int*   eidx  = (const int*)d_in[1];
    const float* eattr = (const float*)d_in[2];
    const int*   iep   = (const int*)d_in[3];
    const int*   iei   = (const int*)d_in[4];
    const float* xyz   = (const float*)d_in[5];
    const float* vecd  = (const float*)d_in[6];
    const int*   a2bi  = (const int*)d_in[7];

    const int n   = in_sizes[0] / 39;
    const int E_  = in_sizes[1] / 2;
    const int EPn = in_sizes[3] / 2;
    const int EIn = in_sizes[4] / 2;
    const int EAn = in_sizes[7] / 2;
    const int Mp  = (n + 127) & ~127;
    const int MB  = (n + 127) / 128;

    const float* gatW[3]  = {(const float*)d_in[9],  (const float*)d_in[15], (const float*)d_in[21]};
    const float* gatWe[3] = {(const float*)d_in[10], (const float*)d_in[16], (const float*)d_in[22]};
    const float* gatAs[3] = {(const float*)d_in[11], (const float*)d_in[17], (const float*)d_in[23]};
    const float* gatAd[3] = {(const float*)d_in[12], (const float*)d_in[18], (const float*)d_in[24]};
    const float* gatAe[3] = {(const float*)d_in[13], (const float*)d_in[19], (const float*)d_in[25]};
    const float* gatB[3]  = {(const float*)d_in[14], (const float*)d_in[20], (const float*)d_in[26]};
    const float* gcnW = (const float*)d_in[27];
    const float* gcnB = (const float*)d_in[28];
    const float* fcnW1 = (const float*)d_in[29];
    const float* fcnB1 = (const float*)d_in[30];
    const float* fcnG  = (const float*)d_in[31];
    const float* fcnBe = (const float*)d_in[32];
    const float* fcnW2 = (const float*)d_in[33];
    const float* fcnB2 = (const float*)d_in[34];

    struct HeadP { const float *W1, *b1, *g, *be, *W2, *b2; };
    HeadP hp[4];
    for (int hh = 0; hh < 4; ++hh) {
        int base = 35 + hh * 6;
        hp[hh] = {(const float*)d_in[base], (const float*)d_in[base + 1], (const float*)d_in[base + 2],
                  (const float*)d_in[base + 3], (const float*)d_in[base + 4], (const float*)d_in[base + 5]};
    }

    char* w = (char*)d_ws;
    size_t off = 0;
    auto alloc = [&](size_t bytes) -> void* {
        void* p = w + off;
        off = (off + bytes + 255) & ~(size_t)255;
        return p;
    };
    int* indeg   = (int*)alloc((size_t)n * 4);
    int* fill    = (int*)alloc((size_t)n * 4);
    int* coff    = (int*)alloc((size_t)(n + 1) * 4);
    int* ceid    = (int*)alloc((size_t)E_ * 4);
    int* pcnt    = (int*)alloc((size_t)n * 4);
    int* pfill   = (int*)alloc((size_t)n * 4);
    int* poff    = (int*)alloc((size_t)(n + 1) * 4);
    int* sid     = (int*)alloc((size_t)EIn * 4);
    float* lattr = (float*)alloc((size_t)n * 27 * 4);
    float* Wea   = (float*)alloc(27 * 4 * 4);
    float* a_e   = (float*)alloc((size_t)(E_ + n) * 4 * 4);
    float* a_s   = (float*)alloc((size_t)n * 4 * 4);
    float* a_d   = (float*)alloc((size_t)n * 4 * 4);
    float* part  = (float*)alloc((size_t)1024 * 2048 * 4);
    float* tmp   = (float*)alloc((size_t)32 * 2048 * 4);
    float* mv    = (float*)alloc(2048 * 4);
    float* W2f   = (float*)alloc((size_t)1024 * 256 * 4);
    float* b2f   = (float*)alloc(256 * 4);
    float* dlink = (float*)alloc((size_t)EIn * 4);
    float* alink = (float*)alloc((size_t)EIn * 4);
    float* dint  = (float*)alloc((size_t)EPn * 4);
    float* aint  = (float*)alloc((size_t)EPn * 4);
    float* feat  = (float*)alloc((size_t)n * 551 * 4);
    float* hbuf  = (float*)alloc((size_t)n * 512 * 4);
    unsigned short* Ab   = (unsigned short*)alloc((size_t)Mp * 576 * 2);
    unsigned short* hidb = (unsigned short*)alloc((size_t)Mp * 1024 * 2);
    unsigned short* embb = (unsigned short*)alloc((size_t)Mp * 256 * 2);
    unsigned short* u0b  = (unsigned short*)alloc((size_t)n * 1024 * 2);
    unsigned short* u1b  = (unsigned short*)alloc((size_t)n * 1024 * 2);
    unsigned short* btB  = (unsigned short*)alloc((size_t)1024 * 1024 * 2);

    hipMemsetAsync(indeg, 0, (size_t)n * 4, stream);
    hipMemsetAsync(fill, 0, (size_t)n * 4, stream);
    hipMemsetAsync(hidb + (size_t)n * 1024, 0, (size_t)(Mp - n) * 1024 * 2, stream);
    hipMemsetAsync(embb + (size_t)n * 256, 0, (size_t)(Mp - n) * 256 * 2, stream);

    const int NCH = 32;
    auto stats_finish = [&](int M, int NB) {
        dim3 g1(8, NCH);
        k_red1<<<g1, 256, 0, stream>>>(part, tmp, NB, NCH);
        k_red2<<<4, 256, 0, stream>>>(tmp, mv, M, NCH);
    };
    auto stageA = [&](const float* src, int lds, int colofs, int K, int Kp) {
        int tot = Mp * Kp;
        k_stage_a<<<(tot + 255) / 256, 256, 0, stream>>>(src, lds, colofs, Ab, Kp, n, K, Mp);
    };
    auto convBt = [&](const float* src, int ldn, int K, int Kp, int N, int Np) {
        int tot = Np * Kp;
        k_conv_bt<<<(tot + 255) / 256, 256, 0, stream>>>(src, ldn, btB, Kp, K, N, Np);
    };
    auto sort_pairs = [&](const int* pidx, int P) {
        hipMemsetAsync(pcnt, 0, (size_t)n * 4, stream);
        hipMemsetAsync(pfill, 0, (size_t)n * 4, stream);
        k_count<<<(P + 255) / 256, 256, 0, stream>>>(pidx, pcnt, P);
        k_scan<<<1, 1024, 0, stream>>>(pcnt, poff, n);
        k_fill<<<(P + 255) / 256, 256, 0, stream>>>(pidx, poff, pfill, sid, P);
    };

    const int* dsta = eidx + E_;
    k_count<<<(E_ + 255) / 256, 256, 0, stream>>>(dsta, indeg, E_);
    k_scan<<<1, 1024, 0, stream>>>(indeg, coff, n);
    k_fill<<<(E_ + 255) / 256, 256, 0, stream>>>(dsta, coff, fill, ceid, E_);
    k_copy_x<<<((n * 39) + 255) / 256, 256, 0, stream>>>(x, feat, n);
    k_loopattr<<<(n + 3) / 4, 128, 0, stream>>>(eattr, coff, ceid, lattr, n);

    const int colofs_in[3] = {0, 39, 167};
    const int fin[3] = {39, 128, 128};
    const int finp[3] = {64, 128, 128};
    for (int l = 0; l < 3; ++l) {
        k_wea<<<1, 128, 0, stream>>>(gatWe[l], gatAe[l], Wea);
        stageA(feat, 551, colofs_in[l], fin[l], finp[l]);
        convBt(gatW[l], 512, fin[l], finp[l], 512, 512);
        dim3 g(4, MB);
        gemm_mfma<0, false, false><<<g, 256, 0, stream>>>(Ab, finp[l], btB, finp[l], nullptr, hbuf, 512, n, 512, finp[l]);
        k_ae<<<(E_ + n + 255) / 256, 256, 0, stream>>>(eattr, lattr, Wea, a_e, E_, n);
        k_asd<<<(n * 4 + 255) / 256, 256, 0, stream>>>(hbuf, gatAs[l], gatAd[l], a_s, a_d, n);
        k_attn<<<n, 64, 0, stream>>>(hbuf, a_s, a_d, a_e, eidx, coff, ceid, gatB[l], feat, 39 + 128 * l, E_);
    }
    // GCN
    {
        stageA(feat, 551, 295, 128, 128);
        convBt(gcnW, 128, 128, 128, 128, 128);
        dim3 g(1, MB);
        gemm_mfma<0, false, false><<<g, 256, 0, stream>>>(Ab, 128, btB, 128, nullptr, hbuf, 128, n, 128, 128);
        k_gcn<<<n, 64, 0, stream>>>(hbuf, eidx, coff, ceid, indeg, gcnB, feat);
    }
    // FCN
    {
        stageA(feat, 551, 0, 551, 576);
        convBt(fcnW1, 1024, 551, 576, 1024, 1024);
        dim3 g(8, MB);
        gemm_mfma<1, true, true><<<g, 256, 0, stream>>>(Ab, 576, btB, 576, fcnB1, hidb, 1024, n, 1024, 576);
        k_stats1b<<<256, 256, 0, stream>>>(hidb, n, part);
        stats_finish(n, 256);
        k_fold<<<256, 256, 0, stream>>>(fcnW2, fcnG, fcnBe, fcnB2, mv, W2f, b2f, 256);
        convBt(W2f, 256, 1024, 1024, 256, 256);
        dim3 g2(2, MB);
        gemm_mfma<1, true, true><<<g2, 256, 0, stream>>>(hidb, 1024, btB, 1024, b2f, embb, 256, n, 256, 1024);
    }
    // pair features
    k_pair<<<(EIn + 255) / 256, 256, 0, stream>>>(iei, xyz, vecd, dlink, alink, EIn);
    k_pair<<<(EPn + 255) / 256, 256, 0, stream>>>(iep, xyz, vecd, dint, aint, EPn);

    float* out = (float*)d_out;
    float* out_link = out;
    float* out_a2b  = out + (size_t)EIn;
    float* out_node = out_a2b + (size_t)EAn * 6;
    float* out_int  = out_node + (size_t)n * 16;

    const dim3 gu(8, MB);

    // ---- link head (NO=1, has d,a extras) ----
    {
        convBt(hp[0].W1, 1024, 256, 256, 1024, 1024);
        gemm_mfma<1, false, false><<<gu, 256, 0, stream>>>(embb, 256, btB, 256, nullptr, u0b, 1024, n, 1024, 256);
        convBt(hp[0].W1 + (size_t)256 * 1024, 1024, 256, 256, 1024, 1024);
        gemm_mfma<1, false, false><<<gu, 256, 0, stream>>>(embb, 256, btB, 256, nullptr, u1b, 1024, n, 1024, 256);
        const float* W1ex = hp[0].W1 + (size_t)512 * 1024;
        sort_pairs(iei, EIn);
        k_pairA<true><<<1024, 256, 0, stream>>>(u0b, u1b, hp[0].b1, W1ex, iei, sid, dlink, alink, EIn, part);
        stats_finish(EIn, 1024);
        k_fold<<<1, 256, 0, stream>>>(hp[0].W2, hp[0].g, hp[0].be, hp[0].b2, mv, W2f, b2f, 1);
        k_pairB<1, true><<<(EIn + 3) / 4, 256, 0, stream>>>(u0b, u1b, hp[0].b1, W1ex, W2f, b2f, iei, sid, dlink, alink, out_link, EIn);
    }
    // ---- a2b head (NO=6, no extras) ----
    {
        convBt(hp[1].W1, 1024, 256, 256, 1024, 1024);
        gemm_mfma<1, false, false><<<gu, 256, 0, stream>>>(embb, 256, btB, 256, nullptr, u0b, 1024, n, 1024, 256);
        convBt(hp[1].W1 + (size_t)256 * 1024, 1024, 256, 256, 1024, 1024);
        gemm_mfma<1, false, false><<<gu, 256, 0, stream>>>(embb, 256, btB, 256, nullptr, u1b, 1024, n, 1024, 256);
        sort_pairs(a2bi, EAn);
        k_pairA<false><<<1024, 256, 0, stream>>>(u0b, u1b, hp[1].b1, nullptr, a2bi, sid, nullptr, nullptr, EAn, part);
        stats_finish(EAn, 1024);
        k_fold<<<6, 256, 0, stream>>>(hp[1].W2, hp[1].g, hp[1].be, hp[1].b2, mv, W2f, b2f, 6);
        k_pairB<6, false><<<(EAn + 3) / 4, 256, 0, stream>>>(u0b, u1b, hp[1].b1, nullptr, W2f, b2f, a2bi, sid, nullptr, nullptr, out_a2b, EAn);
    }
    // ---- node head (NO=16) ----
    {
        convBt(hp[2].W1, 1024, 256, 256, 1024, 1024);
        gemm_mfma<1, true, true><<<gu, 256, 0, stream>>>(embb, 256, btB, 256, hp[2].b1, hidb, 1024, n, 1024, 256);
        k_stats1b<<<256, 256, 0, stream>>>(hidb, n, part);
        stats_finish(n, 256);
        k_fold<<<16, 256, 0, stream>>>(hp[2].W2, hp[2].g, hp[2].be, hp[2].b2, mv, W2f, b2f, 16);
        convBt(W2f, 16, 1024, 1024, 16, 128);
        dim3 g2(1, MB);
        gemm_mfma<0, false, true><<<g2, 256, 0, stream>>>(hidb, 1024, btB, 1024, b2f, out_node, 16, n, 16, 1024);
    }
    // ---- int head (NO=3, has d,a extras) ----
    {
        convBt(hp[3].W1, 1024, 256, 256, 1024, 1024);
        gemm_mfma<1, false, false><<<gu, 256, 0, stream>>>(embb, 256, btB, 256, nullptr, u0b, 1024, n, 1024, 256);
        convBt(hp[3].W1 + (size_t)256 * 1024, 1024, 256, 256, 1024, 1024);
        gemm_mfma<1, false, false><<<gu, 256, 0, stream>>>(embb, 256, btB, 256, nullptr, u1b, 1024, n, 1024, 256);
        const float* W1ex = hp[3].W1 + (size_t)512 * 1024;
        sort_pairs(iep, EPn);
        k_pairA<true><<<1024, 256, 0, stream>>>(u0b, u1b, hp[3].b1, W1ex, iep, sid, dint, aint, EPn, part);
        stats_finish(EPn, 1024);
        k_fold<<<3, 256, 0, stream>>>(hp[3].W2, hp[3].g, hp[3].be, hp[3].b2, mv, W2f, b2f, 3);
        k_pairB<3, true><<<(EPn + 3) / 4, 256, 0, stream>>>(u0b, u1b, hp[3].b1, W1ex, W2f, b2f, iep, sid, dint, aint, out_int, EPn);
    }
}

// Round 6
// 1279.094 us; speedup vs baseline: 1.2368x; 1.2368x over previous
//
#include <hip/hip_runtime.h>
#include <hip/hip_bf16.h>
#include <cstdint>
#include <cstddef>

typedef __attribute__((ext_vector_type(8))) short bf16x8;
typedef __attribute__((ext_vector_type(4))) float f32x4;

__device__ inline float bf2f(unsigned short u) {
    union { float f; unsigned int i; } c; c.i = ((unsigned int)u) << 16; return c.f;
}
__device__ inline unsigned short f2b(float v) {
    __hip_bfloat16 h = __float2bfloat16(v);
    union { __hip_bfloat16 b; unsigned short u; } c; c.b = h; return c.u;
}

__device__ inline float wmax64(float v) {
    #pragma unroll
    for (int o = 32; o; o >>= 1) v = fmaxf(v, __shfl_xor(v, o));
    return v;
}
__device__ inline float wsum64(float v) {
    #pragma unroll
    for (int o = 32; o; o >>= 1) v += __shfl_xor(v, o);
    return v;
}

// ---------------- CSR construction (graph only) ----------------
__global__ void k_count(const int* __restrict__ dst, int* __restrict__ indeg, int E_) {
    int e = blockIdx.x * 256 + threadIdx.x;
    if (e < E_) atomicAdd(&indeg[dst[e]], 1);
}

__global__ __launch_bounds__(1024) void k_scan(const int* __restrict__ indeg, int* __restrict__ coff, int nn) {
    __shared__ int part[1024];
    const int t = threadIdx.x;
    const int CH = (nn + 1023) >> 10;
    int loc[16];
    int s = 0;
    #pragma unroll
    for (int j = 0; j < 16; ++j) {
        if (j < CH) {
            int idx = t * CH + j;
            loc[j] = s;
            s += (idx < nn) ? indeg[idx] : 0;
        }
    }
    part[t] = s;
    __syncthreads();
    for (int o = 1; o < 1024; o <<= 1) {
        int v = (t >= o) ? part[t - o] : 0;
        __syncthreads();
        part[t] += v;
        __syncthreads();
    }
    const int base = (t > 0) ? part[t - 1] : 0;
    #pragma unroll
    for (int j = 0; j < 16; ++j) {
        if (j < CH) {
            int idx = t * CH + j;
            if (idx < nn) coff[idx] = base + loc[j];
        }
    }
    if (t == 1023) coff[nn] = part[1023];
}

__global__ void k_fill(const int* __restrict__ dst, const int* __restrict__ coff,
                       int* __restrict__ fill, int* __restrict__ ceid, int E_) {
    int e = blockIdx.x * 256 + threadIdx.x;
    if (e < E_) {
        int d = dst[e];
        int p = atomicAdd(&fill[d], 1);
        ceid[coff[d] + p] = e;
    }
}

// ---------------- misc small kernels ----------------
__global__ void k_copy_x(const float* __restrict__ x, float* __restrict__ feat, int nn) {
    int t = blockIdx.x * 256 + threadIdx.x;
    if (t < nn * 39) feat[(size_t)(t / 39) * 551 + (t % 39)] = x[t];
}

__global__ __launch_bounds__(128) void k_loopattr(const float* __restrict__ ea, const int* __restrict__ coff,
                                                  const int* __restrict__ ceid, float* __restrict__ la, int nn) {
    int g = blockIdx.x * 4 + (threadIdx.x >> 5);
    int lane = threadIdx.x & 31;
    if (g >= nn || lane >= 27) return;
    int beg = coff[g], cnt = coff[g + 1] - beg;
    float v = 0.f;
    for (int e = 0; e < cnt; ++e) v += ea[(size_t)ceid[beg + e] * 27 + lane];
    la[(size_t)g * 27 + lane] = v / fmaxf((float)cnt, 1.f);
}

__global__ void k_wea(const float* __restrict__ We, const float* __restrict__ aedge, float* __restrict__ Wea) {
    int t = threadIdx.x;
    if (t >= 108) return;
    int f = t >> 2, hh = t & 3;
    float v = 0.f;
    for (int d = 0; d < 128; ++d) v += We[(size_t)f * 512 + hh * 128 + d] * aedge[hh * 128 + d];
    Wea[f * 4 + hh] = v;
}

__global__ void k_ae(const float* __restrict__ ea, const float* __restrict__ la,
                     const float* __restrict__ Wea, float* __restrict__ a_e, int E_, int nn) {
    int r = blockIdx.x * 256 + threadIdx.x;
    if (r >= E_ + nn) return;
    const float* src = (r < E_) ? (ea + (size_t)r * 27) : (la + (size_t)(r - E_) * 27);
    float o0 = 0, o1 = 0, o2 = 0, o3 = 0;
    #pragma unroll
    for (int f = 0; f < 27; ++f) {
        float xv = src[f];
        o0 += xv * Wea[f * 4 + 0];
        o1 += xv * Wea[f * 4 + 1];
        o2 += xv * Wea[f * 4 + 2];
        o3 += xv * Wea[f * 4 + 3];
    }
    a_e[(size_t)r * 4 + 0] = o0; a_e[(size_t)r * 4 + 1] = o1;
    a_e[(size_t)r * 4 + 2] = o2; a_e[(size_t)r * 4 + 3] = o3;
}

__global__ void k_asd(const float* __restrict__ h, const float* __restrict__ asrc,
                      const float* __restrict__ adst, float* __restrict__ a_s,
                      float* __restrict__ a_d, int nn) {
    int t = blockIdx.x * 256 + threadIdx.x;
    if (t >= nn * 4) return;
    int node = t >> 2, hh = t & 3;
    const float* hp = h + (size_t)node * 512 + hh * 128;
    float vs = 0.f, vd = 0.f;
    for (int d = 0; d < 128; ++d) {
        float xv = hp[d];
        vs += xv * asrc[hh * 128 + d];
        vd += xv * adst[hh * 128 + d];
    }
    a_s[t] = vs;
    a_d[t] = vd;
}

// ---------------- GAT attention + aggregation (per node, 1 wave) ----------------
__global__ __launch_bounds__(64) void k_attn(
    const float* __restrict__ h, const float* __restrict__ a_s, const float* __restrict__ a_d,
    const float* __restrict__ a_e, const int* __restrict__ esrc,
    const int* __restrict__ coff, const int* __restrict__ ceid,
    const float* __restrict__ bvec, float* __restrict__ feat, int colofs, int E_) {
    const int i = blockIdx.x;
    const int lane = threadIdx.x;
    const int beg = coff[i];
    const int cnt = coff[i + 1] - beg;
    const int total = cnt + 1;
    const float d0 = a_d[i * 4 + 0], d1 = a_d[i * 4 + 1], d2 = a_d[i * 4 + 2], d3 = a_d[i * 4 + 3];
    float m0 = -1e30f, m1 = -1e30f, m2 = -1e30f, m3 = -1e30f;
    for (int e = lane; e < total; e += 64) {
        int eid, s;
        if (e < cnt) { eid = ceid[beg + e]; s = esrc[eid]; } else { eid = E_ + i; s = i; }
        float l0 = a_s[s * 4 + 0] + d0 + a_e[(size_t)eid * 4 + 0];
        float l1 = a_s[s * 4 + 1] + d1 + a_e[(size_t)eid * 4 + 1];
        float l2 = a_s[s * 4 + 2] + d2 + a_e[(size_t)eid * 4 + 2];
        float l3 = a_s[s * 4 + 3] + d3 + a_e[(size_t)eid * 4 + 3];
        l0 = l0 > 0.f ? l0 : 0.2f * l0;
        l1 = l1 > 0.f ? l1 : 0.2f * l1;
        l2 = l2 > 0.f ? l2 : 0.2f * l2;
        l3 = l3 > 0.f ? l3 : 0.2f * l3;
        m0 = fmaxf(m0, l0); m1 = fmaxf(m1, l1); m2 = fmaxf(m2, l2); m3 = fmaxf(m3, l3);
    }
    m0 = wmax64(m0); m1 = wmax64(m1); m2 = wmax64(m2); m3 = wmax64(m3);
    float s0 = 0, s1 = 0, s2 = 0, s3 = 0;
    for (int e = lane; e < total; e += 64) {
        int eid, s;
        if (e < cnt) { eid = ceid[beg + e]; s = esrc[eid]; } else { eid = E_ + i; s = i; }
        float l0 = a_s[s * 4 + 0] + d0 + a_e[(size_t)eid * 4 + 0];
        float l1 = a_s[s * 4 + 1] + d1 + a_e[(size_t)eid * 4 + 1];
        float l2 = a_s[s * 4 + 2] + d2 + a_e[(size_t)eid * 4 + 2];
        float l3 = a_s[s * 4 + 3] + d3 + a_e[(size_t)eid * 4 + 3];
        l0 = l0 > 0.f ? l0 : 0.2f * l0;
        l1 = l1 > 0.f ? l1 : 0.2f * l1;
        l2 = l2 > 0.f ? l2 : 0.2f * l2;
        l3 = l3 > 0.f ? l3 : 0.2f * l3;
        s0 += __expf(l0 - m0); s1 += __expf(l1 - m1);
        s2 += __expf(l2 - m2); s3 += __expf(l3 - m3);
    }
    s0 = wsum64(s0); s1 = wsum64(s1); s2 = wsum64(s2); s3 = wsum64(s3);
    const int myh = lane >> 4;
    const float mm = myh == 0 ? m0 : myh == 1 ? m1 : myh == 2 ? m2 : m3;
    const float sv = myh == 0 ? s0 : myh == 1 ? s1 : myh == 2 ? s2 : s3;
    const float dd = myh == 0 ? d0 : myh == 1 ? d1 : myh == 2 ? d2 : d3;
    const float iv = 1.f / (sv + 1e-16f);
    float acc[8] = {0, 0, 0, 0, 0, 0, 0, 0};
    for (int e = 0; e < total; ++e) {
        int eid, s;
        if (e < cnt) { eid = ceid[beg + e]; s = esrc[eid]; } else { eid = E_ + i; s = i; }
        float l = a_s[s * 4 + myh] + dd + a_e[(size_t)eid * 4 + myh];
        l = l > 0.f ? l : 0.2f * l;
        const float wgt = __expf(l - mm) * iv;
        const float4* hp = (const float4*)(h + (size_t)s * 512 + lane * 8);
        float4 x0 = hp[0], x1 = hp[1];
        acc[0] += wgt * x0.x; acc[1] += wgt * x0.y; acc[2] += wgt * x0.z; acc[3] += wgt * x0.w;
        acc[4] += wgt * x1.x; acc[5] += wgt * x1.y; acc[6] += wgt * x1.z; acc[7] += wgt * x1.w;
    }
    __shared__ float sh[512];
    #pragma unroll
    for (int j = 0; j < 8; ++j) sh[lane * 8 + j] = acc[j];
    __syncthreads();
    #pragma unroll
    for (int r = 0; r < 2; ++r) {
        int d = lane * 2 + r;
        float v = 0.25f * (sh[d] + sh[128 + d] + sh[256 + d] + sh[384 + d]) + bvec[d];
        feat[(size_t)i * 551 + colofs + d] = fmaxf(v, 0.f);
    }
}

// ---------------- GCN aggregation ----------------
__global__ __launch_bounds__(64) void k_gcn(const float* __restrict__ hg, const int* __restrict__ esrc,
    const int* __restrict__ coff, const int* __restrict__ ceid, const int* __restrict__ indeg,
    const float* __restrict__ bvec, float* __restrict__ feat) {
    const int i = blockIdx.x;
    const int lane = threadIdx.x;
    const int beg = coff[i];
    const int cnt = coff[i + 1] - beg;
    const float di = rsqrtf((float)(indeg[i] + 1));
    const int d = lane * 2;
    float acc0 = hg[(size_t)i * 128 + d] * di;
    float acc1 = hg[(size_t)i * 128 + d + 1] * di;
    for (int e = 0; e < cnt; ++e) {
        int eid = ceid[beg + e];
        int s = esrc[eid];
        float ds = rsqrtf((float)(indeg[s] + 1));
        acc0 += hg[(size_t)s * 128 + d] * ds;
        acc1 += hg[(size_t)s * 128 + d + 1] * ds;
    }
    feat[(size_t)i * 551 + 423 + d] = acc0 * di + bvec[d];
    feat[(size_t)i * 551 + 423 + d + 1] = acc1 * di + bvec[d + 1];
}

// ---------------- packed pair records ----------------
// with extras: int4 {i0, i1, bits(d), bits(a)}; without: int2 {i0, i1}
__global__ void k_pack_ex(const int* __restrict__ idx, const float* __restrict__ xyz,
                          const float* __restrict__ vec, int4* __restrict__ pp, int P) {
    int p = blockIdx.x * 256 + threadIdx.x;
    if (p >= P) return;
    int i = idx[p], j = idx[P + p];
    float dx = xyz[i * 3] - xyz[j * 3];
    float dy = xyz[i * 3 + 1] - xyz[j * 3 + 1];
    float dz = xyz[i * 3 + 2] - xyz[j * 3 + 2];
    float d = dx * dx + dy * dy + dz * dz;
    float a0 = vec[i * 3], a1 = vec[i * 3 + 1], a2 = vec[i * 3 + 2];
    float b0 = vec[j * 3], b1 = vec[j * 3 + 1], b2 = vec[j * 3 + 2];
    float na = fmaxf(sqrtf(a0 * a0 + a1 * a1 + a2 * a2), 1e-8f);
    float nb = fmaxf(sqrtf(b0 * b0 + b1 * b1 + b2 * b2), 1e-8f);
    float a = (a0 * b0 + a1 * b1 + a2 * b2) / (na * nb);
    pp[p] = make_int4(i, j, __float_as_int(d), __float_as_int(a));
}

__global__ void k_pack2(const int* __restrict__ idx, int2* __restrict__ pp, int P) {
    int p = blockIdx.x * 256 + threadIdx.x;
    if (p >= P) return;
    pp[p] = make_int2(idx[p], idx[P + p]);
}

// ---------------- bf16 staging ----------------
__global__ void k_stage_a(const float* __restrict__ src, int lds, int off,
                          unsigned short* __restrict__ dst, int ldd, int M, int K, int Mp) {
    int idx = blockIdx.x * 256 + threadIdx.x;
    if (idx >= Mp * ldd) return;
    int m = idx / ldd, k = idx - m * ldd;
    float v = (m < M && k < K) ? src[(size_t)m * lds + off + k] : 0.f;
    dst[idx] = f2b(v);
}

__global__ void k_conv_bt(const float* __restrict__ src, int ldn,
                          unsigned short* __restrict__ dst, int Kp, int K, int N, int Np) {
    int idx = blockIdx.x * 256 + threadIdx.x;
    if (idx >= Np * Kp) return;
    int nrow = idx / Kp, k = idx - nrow * Kp;
    float v = (nrow < N && k < K) ? src[(size_t)k * ldn + nrow] : 0.f;
    dst[idx] = f2b(v);
}

// ---------------- MFMA bf16 NT-GEMM ----------------
template<int OUT, bool RELU, bool BIAS>
__global__ __launch_bounds__(256) void gemm_mfma(
    const unsigned short* __restrict__ A, int lda,
    const unsigned short* __restrict__ Bt, int ldb,
    const float* __restrict__ bias,
    void* __restrict__ Cv, int ldc,
    int M, int N, int K) {
    const int t = threadIdx.x;
    const int lane = t & 63;
    const int wid = t >> 6;
    const int wm = wid >> 1, wn = wid & 1;
    const int bm0 = blockIdx.y * 128 + wm * 64;
    const int bn0 = blockIdx.x * 128 + wn * 64;
    const int r = lane & 15, g = lane >> 4;
    f32x4 acc[4][4] = {};
    const unsigned short* Ap = A + (size_t)(bm0 + r) * lda + 8 * g;
    const unsigned short* Bp = Bt + (size_t)(bn0 + r) * ldb + 8 * g;
    for (int k0 = 0; k0 < K; k0 += 32) {
        bf16x8 a[4], b[4];
        #pragma unroll
        for (int i = 0; i < 4; ++i) {
            a[i] = *(const bf16x8*)(Ap + (size_t)(i * 16) * lda + k0);
            b[i] = *(const bf16x8*)(Bp + (size_t)(i * 16) * ldb + k0);
        }
        #pragma unroll
        for (int i = 0; i < 4; ++i)
            #pragma unroll
            for (int j = 0; j < 4; ++j)
                acc[i][j] = __builtin_amdgcn_mfma_f32_16x16x32_bf16(a[i], b[j], acc[i][j], 0, 0, 0);
    }
    #pragma unroll
    for (int i = 0; i < 4; ++i) {
        #pragma unroll
        for (int reg = 0; reg < 4; ++reg) {
            const int row = bm0 + i * 16 + 4 * g + reg;
            if (row >= M) continue;
            #pragma unroll
            for (int j = 0; j < 4; ++j) {
                const int col = bn0 + j * 16 + r;
                if (col >= N) continue;
                float v = acc[i][j][reg];
                if constexpr (BIAS) v += bias[col];
                if constexpr (RELU) v = fmaxf(v, 0.f);
                if constexpr (OUT == 0) ((float*)Cv)[(size_t)row * ldc + col] = v;
                else ((unsigned short*)Cv)[(size_t)row * ldc + col] = f2b(v);
            }
        }
    }
}

// ---------------- column stats over bf16 hidden [M,1024] ----------------
__global__ __launch_bounds__(256) void k_stats1b(const unsigned short* __restrict__ Hm, int M, float* __restrict__ part) {
    const int b = blockIdx.x, t = threadIdx.x;
    const int chunk = (M + 255) / 256;
    const int r0 = b * chunk;
    const int r1 = min(M, r0 + chunk);
    float s[4] = {0, 0, 0, 0}, ss[4] = {0, 0, 0, 0};
    for (int r = r0; r < r1; ++r) {
        const ushort4 q = *(const ushort4*)(Hm + (size_t)r * 1024 + t * 4);
        float v0 = bf2f(q.x), v1 = bf2f(q.y), v2 = bf2f(q.z), v3 = bf2f(q.w);
        s[0] += v0; ss[0] += v0 * v0;
        s[1] += v1; ss[1] += v1 * v1;
        s[2] += v2; ss[2] += v2 * v2;
        s[3] += v3; ss[3] += v3 * v3;
    }
    #pragma unroll
    for (int j = 0; j < 4; ++j) {
        part[(size_t)b * 2048 + t * 4 + j] = s[j];
        part[(size_t)b * 2048 + 1024 + t * 4 + j] = ss[j];
    }
}

// ---------------- two-stage parallel column reduce ----------------
__global__ __launch_bounds__(256) void k_red1(const float* __restrict__ part, float* __restrict__ tmp,
                                              int NB, int nch) {
    const int c = blockIdx.x * 256 + threadIdx.x;
    const int ch = blockIdx.y;
    const int per = (NB + nch - 1) / nch;
    const int b0 = ch * per;
    const int b1 = min(NB, b0 + per);
    float s = 0.f;
    for (int b = b0; b < b1; ++b) s += part[(size_t)b * 2048 + c];
    tmp[(size_t)ch * 2048 + c] = s;
}
__global__ void k_red2(const float* __restrict__ tmp, float* __restrict__ mv, int M, int nch) {
    int c = blockIdx.x * 256 + threadIdx.x;
    if (c >= 1024) return;
    float s = 0.f, ss = 0.f;
    for (int ch = 0; ch < nch; ++ch) {
        s += tmp[(size_t)ch * 2048 + c];
        ss += tmp[(size_t)ch * 2048 + 1024 + c];
    }
    float m = s / (float)M;
    float v = ss / (float)M - m * m;
    mv[c] = m;
    mv[1024 + c] = fmaxf(v, 0.f);
}

// ---------------- fold BN into W2 ----------------
__global__ __launch_bounds__(256) void k_fold(const float* __restrict__ W2, const float* __restrict__ g,
    const float* __restrict__ be, const float* __restrict__ b2, const float* __restrict__ mv,
    float* __restrict__ W2f, float* __restrict__ b2f, int NO) {
    const int c = blockIdx.x;
    const int t = threadIdx.x;
    __shared__ float red[256];
    float accb = 0.f;
    for (int k = t; k < 1024; k += 256) {
        float s = (1.f / sqrtf(mv[1024 + k] + 1e-5f)) * g[k];
        float wv = W2[(size_t)k * NO + c];
        W2f[(size_t)k * NO + c] = wv * s;
        accb += (be[k] - mv[k] * s) * wv;
    }
    red[t] = accb;
    __syncthreads();
    for (int o = 128; o; o >>= 1) {
        if (t < o) red[t] += red[t + o];
        __syncthreads();
    }
    if (t == 0) b2f[c] = b2[c] + red[0];
}

// ---------------- pair-head pass A: column stats (packed records, 2x unroll) ----------------
template<bool HASEX>
__global__ __launch_bounds__(256) void k_pairA(
    const unsigned short* __restrict__ u0, const unsigned short* __restrict__ u1,
    const float* __restrict__ b1, const float* __restrict__ W1ex,
    const int4* __restrict__ pp4, const int2* __restrict__ pp2,
    int P, float* __restrict__ part) {
    const int b = blockIdx.x, t = threadIdx.x;
    const int chunk = (P + 1023) / 1024;
    const int r0 = b * chunk;
    const int r1 = min(P, r0 + chunk);
    const float4 bb = *(const float4*)(b1 + t * 4);
    float4 wd = make_float4(0, 0, 0, 0), wa = make_float4(0, 0, 0, 0);
    if constexpr (HASEX) {
        wd = *(const float4*)(W1ex + t * 4);
        wa = *(const float4*)(W1ex + 1024 + t * 4);
    }
    float s[4] = {0, 0, 0, 0}, ss[4] = {0, 0, 0, 0};
    int r = r0;
    for (; r + 1 < r1; r += 2) {
        int i0A, i1A, i0B, i1B;
        float dA = 0, aA = 0, dB = 0, aB = 0;
        if constexpr (HASEX) {
            const int4 rA = pp4[r], rB = pp4[r + 1];
            i0A = rA.x; i1A = rA.y; dA = __int_as_float(rA.z); aA = __int_as_float(rA.w);
            i0B = rB.x; i1B = rB.y; dB = __int_as_float(rB.z); aB = __int_as_float(rB.w);
        } else {
            const int2 rA = pp2[r], rB = pp2[r + 1];
            i0A = rA.x; i1A = rA.y; i0B = rB.x; i1B = rB.y;
        }
        const ushort4 q0A = *(const ushort4*)(u0 + (size_t)i0A * 1024 + t * 4);
        const ushort4 q1A = *(const ushort4*)(u1 + (size_t)i1A * 1024 + t * 4);
        const ushort4 q0B = *(const ushort4*)(u0 + (size_t)i0B * 1024 + t * 4);
        const ushort4 q1B = *(const ushort4*)(u1 + (size_t)i1B * 1024 + t * 4);
        float hA[4], hB[4];
        hA[0] = bf2f(q0A.x) + bf2f(q1A.x) + bb.x;
        hA[1] = bf2f(q0A.y) + bf2f(q1A.y) + bb.y;
        hA[2] = bf2f(q0A.z) + bf2f(q1A.z) + bb.z;
        hA[3] = bf2f(q0A.w) + bf2f(q1A.w) + bb.w;
        hB[0] = bf2f(q0B.x) + bf2f(q1B.x) + bb.x;
        hB[1] = bf2f(q0B.y) + bf2f(q1B.y) + bb.y;
        hB[2] = bf2f(q0B.z) + bf2f(q1B.z) + bb.z;
        hB[3] = bf2f(q0B.w) + bf2f(q1B.w) + bb.w;
        if constexpr (HASEX) {
            hA[0] += dA * wd.x + aA * wa.x; hA[1] += dA * wd.y + aA * wa.y;
            hA[2] += dA * wd.z + aA * wa.z; hA[3] += dA * wd.w + aA * wa.w;
            hB[0] += dB * wd.x + aB * wa.x; hB[1] += dB * wd.y + aB * wa.y;
            hB[2] += dB * wd.z + aB * wa.z; hB[3] += dB * wd.w + aB * wa.w;
        }
        #pragma unroll
        for (int j = 0; j < 4; ++j) {
            float hvA = fmaxf(hA[j], 0.f);
            float hvB = fmaxf(hB[j], 0.f);
            s[j] += hvA + hvB; ss[j] += hvA * hvA + hvB * hvB;
        }
    }
    if (r < r1) {
        int i0, i1;
        float d = 0, a = 0;
        if constexpr (HASEX) {
            const int4 rA = pp4[r];
            i0 = rA.x; i1 = rA.y; d = __int_as_float(rA.z); a = __int_as_float(rA.w);
        } else {
            const int2 rA = pp2[r];
            i0 = rA.x; i1 = rA.y;
        }
        const ushort4 q0 = *(const ushort4*)(u0 + (size_t)i0 * 1024 + t * 4);
        const ushort4 q1 = *(const ushort4*)(u1 + (size_t)i1 * 1024 + t * 4);
        float h[4];
        h[0] = bf2f(q0.x) + bf2f(q1.x) + bb.x;
        h[1] = bf2f(q0.y) + bf2f(q1.y) + bb.y;
        h[2] = bf2f(q0.z) + bf2f(q1.z) + bb.z;
        h[3] = bf2f(q0.w) + bf2f(q1.w) + bb.w;
        if constexpr (HASEX) {
            h[0] += d * wd.x + a * wa.x; h[1] += d * wd.y + a * wa.y;
            h[2] += d * wd.z + a * wa.z; h[3] += d * wd.w + a * wa.w;
        }
        #pragma unroll
        for (int j = 0; j < 4; ++j) {
            float hv = fmaxf(h[j], 0.f);
            s[j] += hv; ss[j] += hv * hv;
        }
    }
    #pragma unroll
    for (int j = 0; j < 4; ++j) {
        part[(size_t)b * 2048 + t * 4 + j] = s[j];
        part[(size_t)b * 2048 + 1024 + t * 4 + j] = ss[j];
    }
}

// ---------------- pair-head pass B: 2 pairs per wave, all loads up-front ----------------
template<int NO, bool HASEX>
__global__ __launch_bounds__(256) void k_pairB(
    const unsigned short* __restrict__ u0, const unsigned short* __restrict__ u1,
    const float* __restrict__ b1, const float* __restrict__ W1ex,
    const float* __restrict__ W2f, const float* __restrict__ b2f,
    const int4* __restrict__ pp4, const int2* __restrict__ pp2,
    float* __restrict__ out, int P) {
    const int t = threadIdx.x;
    const int wid = t >> 6, lane = t & 63;
    const int p0 = (blockIdx.x * 4 + wid) * 2;
    if (p0 >= P) return;
    const int p1 = p0 + 1;
    const bool has1 = p1 < P;
    int i0A, i1A, i0B, i1B;
    float dA = 0, aA = 0, dB = 0, aB = 0;
    if constexpr (HASEX) {
        const int4 rA = pp4[p0];
        const int4 rB = pp4[has1 ? p1 : p0];
        i0A = rA.x; i1A = rA.y; dA = __int_as_float(rA.z); aA = __int_as_float(rA.w);
        i0B = rB.x; i1B = rB.y; dB = __int_as_float(rB.z); aB = __int_as_float(rB.w);
    } else {
        const int2 rA = pp2[p0];
        const int2 rB = pp2[has1 ? p1 : p0];
        i0A = rA.x; i1A = rA.y; i0B = rB.x; i1B = rB.y;
    }
    const int k0 = lane * 16;
    // issue all row loads up-front (8 x 16B)
    union U { uint4 u; unsigned short us[8]; };
    U a0A, a1A, b0A, b1A_, a0B, a1B, b0B, b1B_;
    const unsigned short* pa = u0 + (size_t)i0A * 1024 + k0;
    const unsigned short* pb = u1 + (size_t)i1A * 1024 + k0;
    const unsigned short* pc = u0 + (size_t)i0B * 1024 + k0;
    const unsigned short* pd = u1 + (size_t)i1B * 1024 + k0;
    a0A.u = *(const uint4*)(pa);     a1A.u = *(const uint4*)(pa + 8);
    b0A.u = *(const uint4*)(pb);     b1A_.u = *(const uint4*)(pb + 8);
    a0B.u = *(const uint4*)(pc);     a1B.u = *(const uint4*)(pc + 8);
    b0B.u = *(const uint4*)(pd);     b1B_.u = *(const uint4*)(pd + 8);
    // hoisted parameter vectors
    float4 bbv[4];
    #pragma unroll
    for (int q = 0; q < 4; ++q) bbv[q] = *(const float4*)(b1 + k0 + q * 4);
    float4 wdv[4], wav[4];
    if constexpr (HASEX) {
        #pragma unroll
        for (int q = 0; q < 4; ++q) {
            wdv[q] = *(const float4*)(W1ex + k0 + q * 4);
            wav[q] = *(const float4*)(W1ex + 1024 + k0 + q * 4);
        }
    }
    float accA[NO], accB[NO];
    #pragma unroll
    for (int no = 0; no < NO; ++no) { accA[no] = 0.f; accB[no] = 0.f; }
    #pragma unroll
    for (int j = 0; j < 16; ++j) {
        const int q = j >> 2, c = j & 3;
        const float bbj = (&bbv[q].x)[c];
        float exA = 0.f, exB = 0.f;
        if constexpr (HASEX) {
            const float wdj = (&wdv[q].x)[c], waj = (&wav[q].x)[c];
            exA = dA * wdj + aA * waj;
            exB = dB * wdj + aB * waj;
        }
        const float hAv = (j < 8 ? bf2f(a0A.us[j]) : bf2f(a1A.us[j - 8]))
                        + (j < 8 ? bf2f(b0A.us[j]) : bf2f(b1A_.us[j - 8])) + bbj + exA;
        const float hBv = (j < 8 ? bf2f(a0B.us[j]) : bf2f(a1B.us[j - 8]))
                        + (j < 8 ? bf2f(b0B.us[j]) : bf2f(b1B_.us[j - 8])) + bbj + exB;
        const float rA = fmaxf(hAv, 0.f);
        const float rB = fmaxf(hBv, 0.f);
        const int kk = k0 + j;
        #pragma unroll
        for (int no = 0; no < NO; ++no) {
            const float wv = W2f[(size_t)kk * NO + no];
            accA[no] += rA * wv;
            accB[no] += rB * wv;
        }
    }
    #pragma unroll
    for (int no = 0; no < NO; ++no) {
        float vA = accA[no], vB = accB[no];
        #pragma unroll
        for (int o = 32; o; o >>= 1) { vA += __shfl_down(vA, o); vB += __shfl_down(vB, o); }
        if (lane == 0) {
            out[(size_t)p0 * NO + no] = vA + b2f[no];
            if (has1) out[(size_t)p1 * NO + no] = vB + b2f[no];
        }
    }
}

// ---------------- host driver ----------------
extern "C" void kernel_launch(void* const* d_in, const int* in_sizes, int n_in,
                              void* d_out, int out_size, void* d_ws, size_t ws_size,
                              hipStream_t stream) {
    (void)n_in; (void)out_size; (void)ws_size;
    const float* x     = (const float*)d_in[0];
    const int*   eidx  = (const int*)d_in[1];
    const float* eattr = (const float*)d_in[2];
    const int*   iep   = (const int*)d_in[3];
    const int*   iei   = (const int*)d_in[4];
    const float* xyz   = (const float*)d_in[5];
    const float* vecd  = (const float*)d_in[6];
    const int*   a2bi  = (const int*)d_in[7];

    const int n   = in_sizes[0] / 39;
    const int E_  = in_sizes[1] / 2;
    const int EPn = in_sizes[3] / 2;
    const int EIn = in_sizes[4] / 2;
    const int EAn = in_sizes[7] / 2;
    const int Mp  = (n + 127) & ~127;
    const int MB  = (n + 127) / 128;

    const float* gatW[3]  = {(const float*)d_in[9],  (const float*)d_in[15], (const float*)d_in[21]};
    const float* gatWe[3] = {(const float*)d_in[10], (const float*)d_in[16], (const float*)d_in[22]};
    const float* gatAs[3] = {(const float*)d_in[11], (const float*)d_in[17], (const float*)d_in[23]};
    const float* gatAd[3] = {(const float*)d_in[12], (const float*)d_in[18], (const float*)d_in[24]};
    const float* gatAe[3] = {(const float*)d_in[13], (const float*)d_in[19], (const float*)d_in[25]};
    const float* gatB[3]  = {(const float*)d_in[14], (const float*)d_in[20], (const float*)d_in[26]};
    const float* gcnW = (const float*)d_in[27];
    const float* gcnB = (const float*)d_in[28];
    const float* fcnW1 = (const float*)d_in[29];
    const float* fcnB1 = (const float*)d_in[30];
    const float* fcnG  = (const float*)d_in[31];
    const float* fcnBe = (const float*)d_in[32];
    const float* fcnW2 = (const float*)d_in[33];
    const float* fcnB2 = (const float*)d_in[34];

    struct HeadP { const float *W1, *b1, *g, *be, *W2, *b2; };
    HeadP hp[4];
    for (int hh = 0; hh < 4; ++hh) {
        int base = 35 + hh * 6;
        hp[hh] = {(const float*)d_in[base], (const float*)d_in[base + 1], (const float*)d_in[base + 2],
                  (const float*)d_in[base + 3], (const float*)d_in[base + 4], (const float*)d_in[base + 5]};
    }

    char* w = (char*)d_ws;
    size_t off = 0;
    auto alloc = [&](size_t bytes) -> void* {
        void* p = w + off;
        off = (off + bytes + 255) & ~(size_t)255;
        return p;
    };
    int* indeg   = (int*)alloc((size_t)n * 4);
    int* fill    = (int*)alloc((size_t)n * 4);
    int* coff    = (int*)alloc((size_t)(n + 1) * 4);
    int* ceid    = (int*)alloc((size_t)E_ * 4);
    int4* ppL    = (int4*)alloc((size_t)EIn * 16);
    int2* ppA    = (int2*)alloc((size_t)EAn * 8);
    int4* ppI    = (int4*)alloc((size_t)EPn * 16);
    float* lattr = (float*)alloc((size_t)n * 27 * 4);
    float* Wea   = (float*)alloc(27 * 4 * 4);
    float* a_e   = (float*)alloc((size_t)(E_ + n) * 4 * 4);
    float* a_s   = (float*)alloc((size_t)n * 4 * 4);
    float* a_d   = (float*)alloc((size_t)n * 4 * 4);
    float* part  = (float*)alloc((size_t)1024 * 2048 * 4);
    float* tmp   = (float*)alloc((size_t)32 * 2048 * 4);
    float* mv    = (float*)alloc(2048 * 4);
    float* W2f   = (float*)alloc((size_t)1024 * 256 * 4);
    float* b2f   = (float*)alloc(256 * 4);
    float* feat  = (float*)alloc((size_t)n * 551 * 4);
    float* hbuf  = (float*)alloc((size_t)n * 512 * 4);
    unsigned short* Ab   = (unsigned short*)alloc((size_t)Mp * 576 * 2);
    unsigned short* hidb = (unsigned short*)alloc((size_t)Mp * 1024 * 2);
    unsigned short* embb = (unsigned short*)alloc((size_t)Mp * 256 * 2);
    unsigned short* u0b  = (unsigned short*)alloc((size_t)n * 1024 * 2);
    unsigned short* u1b  = (unsigned short*)alloc((size_t)n * 1024 * 2);
    unsigned short* btB  = (unsigned short*)alloc((size_t)1024 * 1024 * 2);

    hipMemsetAsync(indeg, 0, (size_t)n * 4, stream);
    hipMemsetAsync(fill, 0, (size_t)n * 4, stream);
    hipMemsetAsync(hidb + (size_t)n * 1024, 0, (size_t)(Mp - n) * 1024 * 2, stream);
    hipMemsetAsync(embb + (size_t)n * 256, 0, (size_t)(Mp - n) * 256 * 2, stream);

    const int NCH = 32;
    auto stats_finish = [&](int M, int NB) {
        dim3 g1(8, NCH);
        k_red1<<<g1, 256, 0, stream>>>(part, tmp, NB, NCH);
        k_red2<<<4, 256, 0, stream>>>(tmp, mv, M, NCH);
    };
    auto stageA = [&](const float* src, int lds, int colofs, int K, int Kp) {
        int tot = Mp * Kp;
        k_stage_a<<<(tot + 255) / 256, 256, 0, stream>>>(src, lds, colofs, Ab, Kp, n, K, Mp);
    };
    auto convBt = [&](const float* src, int ldn, int K, int Kp, int N, int Np) {
        int tot = Np * Kp;
        k_conv_bt<<<(tot + 255) / 256, 256, 0, stream>>>(src, ldn, btB, Kp, K, N, Np);
    };

    const int* dsta = eidx + E_;
    k_count<<<(E_ + 255) / 256, 256, 0, stream>>>(dsta, indeg, E_);
    k_scan<<<1, 1024, 0, stream>>>(indeg, coff, n);
    k_fill<<<(E_ + 255) / 256, 256, 0, stream>>>(dsta, coff, fill, ceid, E_);
    k_copy_x<<<((n * 39) + 255) / 256, 256, 0, stream>>>(x, feat, n);
    k_loopattr<<<(n + 3) / 4, 128, 0, stream>>>(eattr, coff, ceid, lattr, n);
    // packed pair records (replaces k_pair + index indirection)
    k_pack_ex<<<(EIn + 255) / 256, 256, 0, stream>>>(iei, xyz, vecd, ppL, EIn);
    k_pack2<<<(EAn + 255) / 256, 256, 0, stream>>>(a2bi, ppA, EAn);
    k_pack_ex<<<(EPn + 255) / 256, 256, 0, stream>>>(iep, xyz, vecd, ppI, EPn);

    const int colofs_in[3] = {0, 39, 167};
    const int fin[3] = {39, 128, 128};
    const int finp[3] = {64, 128, 128};
    for (int l = 0; l < 3; ++l) {
        k_wea<<<1, 128, 0, stream>>>(gatWe[l], gatAe[l], Wea);
        stageA(feat, 551, colofs_in[l], fin[l], finp[l]);
        convBt(gatW[l], 512, fin[l], finp[l], 512, 512);
        dim3 g(4, MB);
        gemm_mfma<0, false, false><<<g, 256, 0, stream>>>(Ab, finp[l], btB, finp[l], nullptr, hbuf, 512, n, 512, finp[l]);
        k_ae<<<(E_ + n + 255) / 256, 256, 0, stream>>>(eattr, lattr, Wea, a_e, E_, n);
        k_asd<<<(n * 4 + 255) / 256, 256, 0, stream>>>(hbuf, gatAs[l], gatAd[l], a_s, a_d, n);
        k_attn<<<n, 64, 0, stream>>>(hbuf, a_s, a_d, a_e, eidx, coff, ceid, gatB[l], feat, 39 + 128 * l, E_);
    }
    // GCN
    {
        stageA(feat, 551, 295, 128, 128);
        convBt(gcnW, 128, 128, 128, 128, 128);
        dim3 g(1, MB);
        gemm_mfma<0, false, false><<<g, 256, 0, stream>>>(Ab, 128, btB, 128, nullptr, hbuf, 128, n, 128, 128);
        k_gcn<<<n, 64, 0, stream>>>(hbuf, eidx, coff, ceid, indeg, gcnB, feat);
    }
    // FCN
    {
        stageA(feat, 551, 0, 551, 576);
        convBt(fcnW1, 1024, 551, 576, 1024, 1024);
        dim3 g(8, MB);
        gemm_mfma<1, true, true><<<g, 256, 0, stream>>>(Ab, 576, btB, 576, fcnB1, hidb, 1024, n, 1024, 576);
        k_stats1b<<<256, 256, 0, stream>>>(hidb, n, part);
        stats_finish(n, 256);
        k_fold<<<256, 256, 0, stream>>>(fcnW2, fcnG, fcnBe, fcnB2, mv, W2f, b2f, 256);
        convBt(W2f, 256, 1024, 1024, 256, 256);
        dim3 g2(2, MB);
        gemm_mfma<1, true, true><<<g2, 256, 0, stream>>>(hidb, 1024, btB, 1024, b2f, embb, 256, n, 256, 1024);
    }

    float* out = (float*)d_out;
    float* out_link = out;
    float* out_a2b  = out + (size_t)EIn;
    float* out_node = out_a2b + (size_t)EAn * 6;
    float* out_int  = out_node + (size_t)n * 16;

    const dim3 gu(8, MB);

    // ---- link head (NO=1, has d,a extras) ----
    {
        convBt(hp[0].W1, 1024, 256, 256, 1024, 1024);
        gemm_mfma<1, false, false><<<gu, 256, 0, stream>>>(embb, 256, btB, 256, nullptr, u0b, 1024, n, 1024, 256);
        convBt(hp[0].W1 + (size_t)256 * 1024, 1024, 256, 256, 1024, 1024);
        gemm_mfma<1, false, false><<<gu, 256, 0, stream>>>(embb, 256, btB, 256, nullptr, u1b, 1024, n, 1024, 256);
        const float* W1ex = hp[0].W1 + (size_t)512 * 1024;
        k_pairA<true><<<1024, 256, 0, stream>>>(u0b, u1b, hp[0].b1, W1ex, ppL, nullptr, EIn, part);
        stats_finish(EIn, 1024);
        k_fold<<<1, 256, 0, stream>>>(hp[0].W2, hp[0].g, hp[0].be, hp[0].b2, mv, W2f, b2f, 1);
        k_pairB<1, true><<<(EIn + 7) / 8, 256, 0, stream>>>(u0b, u1b, hp[0].b1, W1ex, W2f, b2f, ppL, nullptr, out_link, EIn);
    }
    // ---- a2b head (NO=6, no extras) ----
    {
        convBt(hp[1].W1, 1024, 256, 256, 1024, 1024);
        gemm_mfma<1, false, false><<<gu, 256, 0, stream>>>(embb, 256, btB, 256, nullptr, u0b, 1024, n, 1024, 256);
        convBt(hp[1].W1 + (size_t)256 * 1024, 1024, 256, 256, 1024, 1024);
        gemm_mfma<1, false, false><<<gu, 256, 0, stream>>>(embb, 256, btB, 256, nullptr, u1b, 1024, n, 1024, 256);
        k_pairA<false><<<1024, 256, 0, stream>>>(u0b, u1b, hp[1].b1, nullptr, nullptr, ppA, EAn, part);
        stats_finish(EAn, 1024);
        k_fold<<<6, 256, 0, stream>>>(hp[1].W2, hp[1].g, hp[1].be, hp[1].b2, mv, W2f, b2f, 6);
        k_pairB<6, false><<<(EAn + 7) / 8, 256, 0, stream>>>(u0b, u1b, hp[1].b1, nullptr, W2f, b2f, nullptr, ppA, out_a2b, EAn);
    }
    // ---- node head (NO=16) ----
    {
        convBt(hp[2].W1, 1024, 256, 256, 1024, 1024);
        gemm_mfma<1, true, true><<<gu, 256, 0, stream>>>(embb, 256, btB, 256, hp[2].b1, hidb, 1024, n, 1024, 256);
        k_stats1b<<<256, 256, 0, stream>>>(hidb, n, part);
        stats_finish(n, 256);
        k_fold<<<16, 256, 0, stream>>>(hp[2].W2, hp[2].g, hp[2].be, hp[2].b2, mv, W2f, b2f, 16);
        convBt(W2f, 16, 1024, 1024, 16, 128);
        dim3 g2(1, MB);
        gemm_mfma<0, false, true><<<g2, 256, 0, stream>>>(hidb, 1024, btB, 1024, b2f, out_node, 16, n, 16, 1024);
    }
    // ---- int head (NO=3, has d,a extras) ----
    {
        convBt(hp[3].W1, 1024, 256, 256, 1024, 1024);
        gemm_mfma<1, false, false><<<gu, 256, 0, stream>>>(embb, 256, btB, 256, nullptr, u0b, 1024, n, 1024, 256);
        convBt(hp[3].W1 + (size_t)256 * 1024, 1024, 256, 256, 1024, 1024);
        gemm_mfma<1, false, false><<<gu, 256, 0, stream>>>(embb, 256, btB, 256, nullptr, u1b, 1024, n, 1024, 256);
        const float* W1ex = hp[3].W1 + (size_t)512 * 1024;
        k_pairA<true><<<1024, 256, 0, stream>>>(u0b, u1b, hp[3].b1, W1ex, ppI, nullptr, EPn, part);
        stats_finish(EPn, 1024);
        k_fold<<<3, 256, 0, stream>>>(hp[3].W2, hp[3].g, hp[3].be, hp[3].b2, mv, W2f, b2f, 3);
        k_pairB<3, true><<<(EPn + 7) / 8, 256, 0, stream>>>(u0b, u1b, hp[3].b1, W1ex, W2f, b2f, ppI, nullptr, out_int, EPn);
    }
}

// Round 7
// 1179.512 us; speedup vs baseline: 1.3412x; 1.0844x over previous
//
#include <hip/hip_runtime.h>
#include <hip/hip_bf16.h>
#include <cstdint>
#include <cstddef>

typedef __attribute__((ext_vector_type(8))) short bf16x8;
typedef __attribute__((ext_vector_type(4))) float f32x4;

__device__ inline float bf2f(unsigned short u) {
    union { float f; unsigned int i; } c; c.i = ((unsigned int)u) << 16; return c.f;
}
__device__ inline unsigned short f2b(float v) {
    __hip_bfloat16 h = __float2bfloat16(v);
    union { __hip_bfloat16 b; unsigned short u; } c; c.b = h; return c.u;
}

__device__ inline float wmax64(float v) {
    #pragma unroll
    for (int o = 32; o; o >>= 1) v = fmaxf(v, __shfl_xor(v, o));
    return v;
}
__device__ inline float wsum64(float v) {
    #pragma unroll
    for (int o = 32; o; o >>= 1) v += __shfl_xor(v, o);
    return v;
}

// ---------------- CSR / bucket construction ----------------
__global__ void k_count(const int* __restrict__ dst, int* __restrict__ indeg, int E_) {
    int e = blockIdx.x * 256 + threadIdx.x;
    if (e < E_) atomicAdd(&indeg[dst[e]], 1);
}

__global__ __launch_bounds__(1024) void k_scan(const int* __restrict__ indeg, int* __restrict__ coff, int nn) {
    __shared__ int part[1024];
    const int t = threadIdx.x;
    const int CH = (nn + 1023) >> 10;
    int loc[16];
    int s = 0;
    #pragma unroll
    for (int j = 0; j < 16; ++j) {
        if (j < CH) {
            int idx = t * CH + j;
            loc[j] = s;
            s += (idx < nn) ? indeg[idx] : 0;
        }
    }
    part[t] = s;
    __syncthreads();
    for (int o = 1; o < 1024; o <<= 1) {
        int v = (t >= o) ? part[t - o] : 0;
        __syncthreads();
        part[t] += v;
        __syncthreads();
    }
    const int base = (t > 0) ? part[t - 1] : 0;
    #pragma unroll
    for (int j = 0; j < 16; ++j) {
        if (j < CH) {
            int idx = t * CH + j;
            if (idx < nn) coff[idx] = base + loc[j];
        }
    }
    if (t == 1023) coff[nn] = part[1023];
}

__global__ void k_fill(const int* __restrict__ dst, const int* __restrict__ coff,
                       int* __restrict__ fill, int* __restrict__ ceid, int E_) {
    int e = blockIdx.x * 256 + threadIdx.x;
    if (e < E_) {
        int d = dst[e];
        int p = atomicAdd(&fill[d], 1);
        ceid[coff[d] + p] = e;
    }
}

// pack pair records scattered into i0-bucketed order; sord[pos] = original pair id
template<bool HASEX>
__global__ void k_pack_sorted(const int* __restrict__ idx, const float* __restrict__ xyz,
                              const float* __restrict__ vec, const int* __restrict__ poff,
                              int* __restrict__ pfill, int4* __restrict__ spp,
                              int* __restrict__ sord, int P) {
    int p = blockIdx.x * 256 + threadIdx.x;
    if (p >= P) return;
    int i = idx[p], j = idx[P + p];
    float d = 0.f, a = 0.f;
    if constexpr (HASEX) {
        float dx = xyz[i * 3] - xyz[j * 3];
        float dy = xyz[i * 3 + 1] - xyz[j * 3 + 1];
        float dz = xyz[i * 3 + 2] - xyz[j * 3 + 2];
        d = dx * dx + dy * dy + dz * dz;
        float a0 = vec[i * 3], a1 = vec[i * 3 + 1], a2 = vec[i * 3 + 2];
        float b0 = vec[j * 3], b1 = vec[j * 3 + 1], b2 = vec[j * 3 + 2];
        float na = fmaxf(sqrtf(a0 * a0 + a1 * a1 + a2 * a2), 1e-8f);
        float nb = fmaxf(sqrtf(b0 * b0 + b1 * b1 + b2 * b2), 1e-8f);
        a = (a0 * b0 + a1 * b1 + a2 * b2) / (na * nb);
    }
    int pos = poff[i] + atomicAdd(&pfill[i], 1);
    spp[pos] = make_int4(i, j, __float_as_int(d), __float_as_int(a));
    sord[pos] = p;
}

// ---------------- misc small kernels ----------------
__global__ void k_copy_x(const float* __restrict__ x, float* __restrict__ feat, int nn) {
    int t = blockIdx.x * 256 + threadIdx.x;
    if (t < nn * 39) feat[(size_t)(t / 39) * 551 + (t % 39)] = x[t];
}

__global__ __launch_bounds__(128) void k_loopattr(const float* __restrict__ ea, const int* __restrict__ coff,
                                                  const int* __restrict__ ceid, float* __restrict__ la, int nn) {
    int g = blockIdx.x * 4 + (threadIdx.x >> 5);
    int lane = threadIdx.x & 31;
    if (g >= nn || lane >= 27) return;
    int beg = coff[g], cnt = coff[g + 1] - beg;
    float v = 0.f;
    for (int e = 0; e < cnt; ++e) v += ea[(size_t)ceid[beg + e] * 27 + lane];
    la[(size_t)g * 27 + lane] = v / fmaxf((float)cnt, 1.f);
}

__global__ void k_wea(const float* __restrict__ We, const float* __restrict__ aedge, float* __restrict__ Wea) {
    int t = threadIdx.x;
    if (t >= 108) return;
    int f = t >> 2, hh = t & 3;
    float v = 0.f;
    for (int d = 0; d < 128; ++d) v += We[(size_t)f * 512 + hh * 128 + d] * aedge[hh * 128 + d];
    Wea[f * 4 + hh] = v;
}

__global__ void k_ae(const float* __restrict__ ea, const float* __restrict__ la,
                     const float* __restrict__ Wea, float* __restrict__ a_e, int E_, int nn) {
    int r = blockIdx.x * 256 + threadIdx.x;
    if (r >= E_ + nn) return;
    const float* src = (r < E_) ? (ea + (size_t)r * 27) : (la + (size_t)(r - E_) * 27);
    float o0 = 0, o1 = 0, o2 = 0, o3 = 0;
    #pragma unroll
    for (int f = 0; f < 27; ++f) {
        float xv = src[f];
        o0 += xv * Wea[f * 4 + 0];
        o1 += xv * Wea[f * 4 + 1];
        o2 += xv * Wea[f * 4 + 2];
        o3 += xv * Wea[f * 4 + 3];
    }
    a_e[(size_t)r * 4 + 0] = o0; a_e[(size_t)r * 4 + 1] = o1;
    a_e[(size_t)r * 4 + 2] = o2; a_e[(size_t)r * 4 + 3] = o3;
}

// h table is bf16 [n,512]
__global__ void k_asd(const unsigned short* __restrict__ hb, const float* __restrict__ asrc,
                      const float* __restrict__ adst, float* __restrict__ a_s,
                      float* __restrict__ a_d, int nn) {
    int t = blockIdx.x * 256 + threadIdx.x;
    if (t >= nn * 4) return;
    int node = t >> 2, hh = t & 3;
    const unsigned short* hp = hb + (size_t)node * 512 + hh * 128;
    float vs = 0.f, vd = 0.f;
    #pragma unroll
    for (int q = 0; q < 16; ++q) {
        union { uint4 u; unsigned short us[8]; } c;
        c.u = *(const uint4*)(hp + q * 8);
        #pragma unroll
        for (int j = 0; j < 8; ++j) {
            float xv = bf2f(c.us[j]);
            vs += xv * asrc[hh * 128 + q * 8 + j];
            vd += xv * adst[hh * 128 + q * 8 + j];
        }
    }
    a_s[t] = vs;
    a_d[t] = vd;
}

// ---------------- GAT attention + aggregation (per node, 1 wave, bf16 h) ----------------
__global__ __launch_bounds__(64) void k_attn(
    const unsigned short* __restrict__ hb, const float* __restrict__ a_s, const float* __restrict__ a_d,
    const float* __restrict__ a_e, const int* __restrict__ esrc,
    const int* __restrict__ coff, const int* __restrict__ ceid,
    const float* __restrict__ bvec, float* __restrict__ feat, int colofs, int E_) {
    const int i = blockIdx.x;
    const int lane = threadIdx.x;
    const int beg = coff[i];
    const int cnt = coff[i + 1] - beg;
    const int total = cnt + 1;
    const float d0 = a_d[i * 4 + 0], d1 = a_d[i * 4 + 1], d2 = a_d[i * 4 + 2], d3 = a_d[i * 4 + 3];
    float m0 = -1e30f, m1 = -1e30f, m2 = -1e30f, m3 = -1e30f;
    for (int e = lane; e < total; e += 64) {
        int eid, s;
        if (e < cnt) { eid = ceid[beg + e]; s = esrc[eid]; } else { eid = E_ + i; s = i; }
        float l0 = a_s[s * 4 + 0] + d0 + a_e[(size_t)eid * 4 + 0];
        float l1 = a_s[s * 4 + 1] + d1 + a_e[(size_t)eid * 4 + 1];
        float l2 = a_s[s * 4 + 2] + d2 + a_e[(size_t)eid * 4 + 2];
        float l3 = a_s[s * 4 + 3] + d3 + a_e[(size_t)eid * 4 + 3];
        l0 = l0 > 0.f ? l0 : 0.2f * l0;
        l1 = l1 > 0.f ? l1 : 0.2f * l1;
        l2 = l2 > 0.f ? l2 : 0.2f * l2;
        l3 = l3 > 0.f ? l3 : 0.2f * l3;
        m0 = fmaxf(m0, l0); m1 = fmaxf(m1, l1); m2 = fmaxf(m2, l2); m3 = fmaxf(m3, l3);
    }
    m0 = wmax64(m0); m1 = wmax64(m1); m2 = wmax64(m2); m3 = wmax64(m3);
    float s0 = 0, s1 = 0, s2 = 0, s3 = 0;
    for (int e = lane; e < total; e += 64) {
        int eid, s;
        if (e < cnt) { eid = ceid[beg + e]; s = esrc[eid]; } else { eid = E_ + i; s = i; }
        float l0 = a_s[s * 4 + 0] + d0 + a_e[(size_t)eid * 4 + 0];
        float l1 = a_s[s * 4 + 1] + d1 + a_e[(size_t)eid * 4 + 1];
        float l2 = a_s[s * 4 + 2] + d2 + a_e[(size_t)eid * 4 + 2];
        float l3 = a_s[s * 4 + 3] + d3 + a_e[(size_t)eid * 4 + 3];
        l0 = l0 > 0.f ? l0 : 0.2f * l0;
        l1 = l1 > 0.f ? l1 : 0.2f * l1;
        l2 = l2 > 0.f ? l2 : 0.2f * l2;
        l3 = l3 > 0.f ? l3 : 0.2f * l3;
        s0 += __expf(l0 - m0); s1 += __expf(l1 - m1);
        s2 += __expf(l2 - m2); s3 += __expf(l3 - m3);
    }
    s0 = wsum64(s0); s1 = wsum64(s1); s2 = wsum64(s2); s3 = wsum64(s3);
    const int myh = lane >> 4;
    const float mm = myh == 0 ? m0 : myh == 1 ? m1 : myh == 2 ? m2 : m3;
    const float sv = myh == 0 ? s0 : myh == 1 ? s1 : myh == 2 ? s2 : s3;
    const float dd = myh == 0 ? d0 : myh == 1 ? d1 : myh == 2 ? d2 : d3;
    const float iv = 1.f / (sv + 1e-16f);
    float acc[8] = {0, 0, 0, 0, 0, 0, 0, 0};
    for (int e = 0; e < total; ++e) {
        int eid, s;
        if (e < cnt) { eid = ceid[beg + e]; s = esrc[eid]; } else { eid = E_ + i; s = i; }
        float l = a_s[s * 4 + myh] + dd + a_e[(size_t)eid * 4 + myh];
        l = l > 0.f ? l : 0.2f * l;
        const float wgt = __expf(l - mm) * iv;
        union { uint4 u; unsigned short us[8]; } c;
        c.u = *(const uint4*)(hb + (size_t)s * 512 + lane * 8);
        #pragma unroll
        for (int j = 0; j < 8; ++j) acc[j] += wgt * bf2f(c.us[j]);
    }
    __shared__ float sh[512];
    #pragma unroll
    for (int j = 0; j < 8; ++j) sh[lane * 8 + j] = acc[j];
    __syncthreads();
    #pragma unroll
    for (int r = 0; r < 2; ++r) {
        int d = lane * 2 + r;
        float v = 0.25f * (sh[d] + sh[128 + d] + sh[256 + d] + sh[384 + d]) + bvec[d];
        feat[(size_t)i * 551 + colofs + d] = fmaxf(v, 0.f);
    }
}

// ---------------- GCN aggregation (bf16 hg [n,128]) ----------------
__global__ __launch_bounds__(64) void k_gcn(const unsigned short* __restrict__ hg, const int* __restrict__ esrc,
    const int* __restrict__ coff, const int* __restrict__ ceid, const int* __restrict__ indeg,
    const float* __restrict__ bvec, float* __restrict__ feat) {
    const int i = blockIdx.x;
    const int lane = threadIdx.x;
    const int beg = coff[i];
    const int cnt = coff[i + 1] - beg;
    const float di = rsqrtf((float)(indeg[i] + 1));
    const int d = lane * 2;
    unsigned int u0 = *(const unsigned int*)(hg + (size_t)i * 128 + d);
    float acc0 = bf2f((unsigned short)(u0 & 0xffff)) * di;
    float acc1 = bf2f((unsigned short)(u0 >> 16)) * di;
    for (int e = 0; e < cnt; ++e) {
        int eid = ceid[beg + e];
        int s = esrc[eid];
        float ds = rsqrtf((float)(indeg[s] + 1));
        unsigned int u = *(const unsigned int*)(hg + (size_t)s * 128 + d);
        acc0 += bf2f((unsigned short)(u & 0xffff)) * ds;
        acc1 += bf2f((unsigned short)(u >> 16)) * ds;
    }
    feat[(size_t)i * 551 + 423 + d] = acc0 * di + bvec[d];
    feat[(size_t)i * 551 + 423 + d + 1] = acc1 * di + bvec[d + 1];
}

// ---------------- bf16 staging ----------------
__global__ void k_stage_a(const float* __restrict__ src, int lds, int off,
                          unsigned short* __restrict__ dst, int ldd, int M, int K, int Mp) {
    int idx = blockIdx.x * 256 + threadIdx.x;
    if (idx >= Mp * ldd) return;
    int m = idx / ldd, k = idx - m * ldd;
    float v = (m < M && k < K) ? src[(size_t)m * lds + off + k] : 0.f;
    dst[idx] = f2b(v);
}

__global__ void k_conv_bt(const float* __restrict__ src, int ldn,
                          unsigned short* __restrict__ dst, int Kp, int K, int N, int Np) {
    int idx = blockIdx.x * 256 + threadIdx.x;
    if (idx >= Np * Kp) return;
    int nrow = idx / Kp, k = idx - nrow * Kp;
    float v = (nrow < N && k < K) ? src[(size_t)k * ldn + nrow] : 0.f;
    dst[idx] = f2b(v);
}

// combined u0|u1 weight: dst[2048,256]; rows 0..1023 = W1[0:256] cols, rows 1024.. = W1[256:512] cols
__global__ void k_conv_bt2(const float* __restrict__ W1, unsigned short* __restrict__ dst) {
    int idx = blockIdx.x * 256 + threadIdx.x;
    if (idx >= 2048 * 256) return;
    int nrow = idx >> 8, k = idx & 255;
    float v = (nrow < 1024) ? W1[(size_t)k * 1024 + nrow]
                            : W1[(size_t)(256 + k) * 1024 + (nrow - 1024)];
    dst[idx] = f2b(v);
}

// ---------------- MFMA bf16 NT-GEMM ----------------
template<int OUT, bool RELU, bool BIAS>
__global__ __launch_bounds__(256) void gemm_mfma(
    const unsigned short* __restrict__ A, int lda,
    const unsigned short* __restrict__ Bt, int ldb,
    const float* __restrict__ bias,
    void* __restrict__ Cv, int ldc,
    int M, int N, int K) {
    const int t = threadIdx.x;
    const int lane = t & 63;
    const int wid = t >> 6;
    const int wm = wid >> 1, wn = wid & 1;
    const int bm0 = blockIdx.y * 128 + wm * 64;
    const int bn0 = blockIdx.x * 128 + wn * 64;
    const int r = lane & 15, g = lane >> 4;
    f32x4 acc[4][4] = {};
    const unsigned short* Ap = A + (size_t)(bm0 + r) * lda + 8 * g;
    const unsigned short* Bp = Bt + (size_t)(bn0 + r) * ldb + 8 * g;
    for (int k0 = 0; k0 < K; k0 += 32) {
        bf16x8 a[4], b[4];
        #pragma unroll
        for (int i = 0; i < 4; ++i) {
            a[i] = *(const bf16x8*)(Ap + (size_t)(i * 16) * lda + k0);
            b[i] = *(const bf16x8*)(Bp + (size_t)(i * 16) * ldb + k0);
        }
        #pragma unroll
        for (int i = 0; i < 4; ++i)
            #pragma unroll
            for (int j = 0; j < 4; ++j)
                acc[i][j] = __builtin_amdgcn_mfma_f32_16x16x32_bf16(a[i], b[j], acc[i][j], 0, 0, 0);
    }
    #pragma unroll
    for (int i = 0; i < 4; ++i) {
        #pragma unroll
        for (int reg = 0; reg < 4; ++reg) {
            const int row = bm0 + i * 16 + 4 * g + reg;
            if (row >= M) continue;
            #pragma unroll
            for (int j = 0; j < 4; ++j) {
                const int col = bn0 + j * 16 + r;
                if (col >= N) continue;
                float v = acc[i][j][reg];
                if constexpr (BIAS) v += bias[col];
                if constexpr (RELU) v = fmaxf(v, 0.f);
                if constexpr (OUT == 0) ((float*)Cv)[(size_t)row * ldc + col] = v;
                else ((unsigned short*)Cv)[(size_t)row * ldc + col] = f2b(v);
            }
        }
    }
}

// ---------------- column stats over bf16 hidden [M,1024] ----------------
__global__ __launch_bounds__(256) void k_stats1b(const unsigned short* __restrict__ Hm, int M, float* __restrict__ part) {
    const int b = blockIdx.x, t = threadIdx.x;
    const int chunk = (M + 255) / 256;
    const int r0 = b * chunk;
    const int r1 = min(M, r0 + chunk);
    float s[4] = {0, 0, 0, 0}, ss[4] = {0, 0, 0, 0};
    for (int r = r0; r < r1; ++r) {
        const ushort4 q = *(const ushort4*)(Hm + (size_t)r * 1024 + t * 4);
        float v0 = bf2f(q.x), v1 = bf2f(q.y), v2 = bf2f(q.z), v3 = bf2f(q.w);
        s[0] += v0; ss[0] += v0 * v0;
        s[1] += v1; ss[1] += v1 * v1;
        s[2] += v2; ss[2] += v2 * v2;
        s[3] += v3; ss[3] += v3 * v3;
    }
    #pragma unroll
    for (int j = 0; j < 4; ++j) {
        part[(size_t)b * 2048 + t * 4 + j] = s[j];
        part[(size_t)b * 2048 + 1024 + t * 4 + j] = ss[j];
    }
}

// ---------------- two-stage parallel column reduce ----------------
__global__ __launch_bounds__(256) void k_red1(const float* __restrict__ part, float* __restrict__ tmp,
                                              int NB, int nch) {
    const int c = blockIdx.x * 256 + threadIdx.x;
    const int ch = blockIdx.y;
    const int per = (NB + nch - 1) / nch;
    const int b0 = ch * per;
    const int b1 = min(NB, b0 + per);
    float s = 0.f;
    for (int b = b0; b < b1; ++b) s += part[(size_t)b * 2048 + c];
    tmp[(size_t)ch * 2048 + c] = s;
}
__global__ void k_red2(const float* __restrict__ tmp, float* __restrict__ mv, int M, int nch) {
    int c = blockIdx.x * 256 + threadIdx.x;
    if (c >= 1024) return;
    float s = 0.f, ss = 0.f;
    for (int ch = 0; ch < nch; ++ch) {
        s += tmp[(size_t)ch * 2048 + c];
        ss += tmp[(size_t)ch * 2048 + 1024 + c];
    }
    float m = s / (float)M;
    float v = ss / (float)M - m * m;
    mv[c] = m;
    mv[1024 + c] = fmaxf(v, 0.f);
}

// ---------------- fold BN into W2 ----------------
__global__ __launch_bounds__(256) void k_fold(const float* __restrict__ W2, const float* __restrict__ g,
    const float* __restrict__ be, const float* __restrict__ b2, const float* __restrict__ mv,
    float* __restrict__ W2f, float* __restrict__ b2f, int NO) {
    const int c = blockIdx.x;
    const int t = threadIdx.x;
    __shared__ float red[256];
    float accb = 0.f;
    for (int k = t; k < 1024; k += 256) {
        float s = (1.f / sqrtf(mv[1024 + k] + 1e-5f)) * g[k];
        float wv = W2[(size_t)k * NO + c];
        W2f[(size_t)k * NO + c] = wv * s;
        accb += (be[k] - mv[k] * s) * wv;
    }
    red[t] = accb;
    __syncthreads();
    for (int o = 128; o; o >>= 1) {
        if (t < o) red[t] += red[t + o];
        __syncthreads();
    }
    if (t == 0) b2f[c] = b2[c] + red[0];
}

// ---------------- pair-head pass A: column stats (bucketed records, 2x unroll) ----------------
template<bool HASEX>
__global__ __launch_bounds__(256) void k_pairA(
    const unsigned short* __restrict__ u0, const unsigned short* __restrict__ u1, int ldu,
    const float* __restrict__ b1, const float* __restrict__ W1ex,
    const int4* __restrict__ spp,
    int P, float* __restrict__ part) {
    const int b = blockIdx.x, t = threadIdx.x;
    const int chunk = (P + 1023) / 1024;
    const int r0 = b * chunk;
    const int r1 = min(P, r0 + chunk);
    const float4 bb = *(const float4*)(b1 + t * 4);
    float4 wd = make_float4(0, 0, 0, 0), wa = make_float4(0, 0, 0, 0);
    if constexpr (HASEX) {
        wd = *(const float4*)(W1ex + t * 4);
        wa = *(const float4*)(W1ex + 1024 + t * 4);
    }
    float s[4] = {0, 0, 0, 0}, ss[4] = {0, 0, 0, 0};
    int r = r0;
    for (; r + 1 < r1; r += 2) {
        const int4 rA = spp[r], rB = spp[r + 1];
        const int i0A = rA.x, i1A = rA.y, i0B = rB.x, i1B = rB.y;
        float dA = 0, aA = 0, dB = 0, aB = 0;
        if constexpr (HASEX) {
            dA = __int_as_float(rA.z); aA = __int_as_float(rA.w);
            dB = __int_as_float(rB.z); aB = __int_as_float(rB.w);
        }
        const ushort4 q0A = *(const ushort4*)(u0 + (size_t)i0A * ldu + t * 4);
        const ushort4 q1A = *(const ushort4*)(u1 + (size_t)i1A * ldu + t * 4);
        const ushort4 q0B = *(const ushort4*)(u0 + (size_t)i0B * ldu + t * 4);
        const ushort4 q1B = *(const ushort4*)(u1 + (size_t)i1B * ldu + t * 4);
        float hA[4], hB[4];
        hA[0] = bf2f(q0A.x) + bf2f(q1A.x) + bb.x;
        hA[1] = bf2f(q0A.y) + bf2f(q1A.y) + bb.y;
        hA[2] = bf2f(q0A.z) + bf2f(q1A.z) + bb.z;
        hA[3] = bf2f(q0A.w) + bf2f(q1A.w) + bb.w;
        hB[0] = bf2f(q0B.x) + bf2f(q1B.x) + bb.x;
        hB[1] = bf2f(q0B.y) + bf2f(q1B.y) + bb.y;
        hB[2] = bf2f(q0B.z) + bf2f(q1B.z) + bb.z;
        hB[3] = bf2f(q0B.w) + bf2f(q1B.w) + bb.w;
        if constexpr (HASEX) {
            hA[0] += dA * wd.x + aA * wa.x; hA[1] += dA * wd.y + aA * wa.y;
            hA[2] += dA * wd.z + aA * wa.z; hA[3] += dA * wd.w + aA * wa.w;
            hB[0] += dB * wd.x + aB * wa.x; hB[1] += dB * wd.y + aB * wa.y;
            hB[2] += dB * wd.z + aB * wa.z; hB[3] += dB * wd.w + aB * wa.w;
        }
        #pragma unroll
        for (int j = 0; j < 4; ++j) {
            float hvA = fmaxf(hA[j], 0.f);
            float hvB = fmaxf(hB[j], 0.f);
            s[j] += hvA + hvB; ss[j] += hvA * hvA + hvB * hvB;
        }
    }
    if (r < r1) {
        const int4 rA = spp[r];
        const int i0 = rA.x, i1 = rA.y;
        float d = 0, a = 0;
        if constexpr (HASEX) { d = __int_as_float(rA.z); a = __int_as_float(rA.w); }
        const ushort4 q0 = *(const ushort4*)(u0 + (size_t)i0 * ldu + t * 4);
        const ushort4 q1 = *(const ushort4*)(u1 + (size_t)i1 * ldu + t * 4);
        float h[4];
        h[0] = bf2f(q0.x) + bf2f(q1.x) + bb.x;
        h[1] = bf2f(q0.y) + bf2f(q1.y) + bb.y;
        h[2] = bf2f(q0.z) + bf2f(q1.z) + bb.z;
        h[3] = bf2f(q0.w) + bf2f(q1.w) + bb.w;
        if constexpr (HASEX) {
            h[0] += d * wd.x + a * wa.x; h[1] += d * wd.y + a * wa.y;
            h[2] += d * wd.z + a * wa.z; h[3] += d * wd.w + a * wa.w;
        }
        #pragma unroll
        for (int j = 0; j < 4; ++j) {
            float hv = fmaxf(h[j], 0.f);
            s[j] += hv; ss[j] += hv * hv;
        }
    }
    #pragma unroll
    for (int j = 0; j < 4; ++j) {
        part[(size_t)b * 2048 + t * 4 + j] = s[j];
        part[(size_t)b * 2048 + 1024 + t * 4 + j] = ss[j];
    }
}

// ---------------- pair-head pass B: 2 bucketed pairs per wave, scatter by sord ----------------
template<int NO, bool HASEX>
__global__ __launch_bounds__(256) void k_pairB(
    const unsigned short* __restrict__ u0, const unsigned short* __restrict__ u1, int ldu,
    const float* __restrict__ b1, const float* __restrict__ W1ex,
    const float* __restrict__ W2f, const float* __restrict__ b2f,
    const int4* __restrict__ spp, const int* __restrict__ sord,
    float* __restrict__ out, int P) {
    const int t = threadIdx.x;
    const int wid = t >> 6, lane = t & 63;
    const int p0 = (blockIdx.x * 4 + wid) * 2;
    if (p0 >= P) return;
    const int p1 = p0 + 1;
    const bool has1 = p1 < P;
    const int4 rA = spp[p0];
    const int4 rB = spp[has1 ? p1 : p0];
    const int i0A = rA.x, i1A = rA.y, i0B = rB.x, i1B = rB.y;
    float dA = 0, aA = 0, dB = 0, aB = 0;
    if constexpr (HASEX) {
        dA = __int_as_float(rA.z); aA = __int_as_float(rA.w);
        dB = __int_as_float(rB.z); aB = __int_as_float(rB.w);
    }
    const int k0 = lane * 16;
    union U { uint4 u; unsigned short us[8]; };
    U a0A, a1A, b0A, b1A_, a0B, a1B, b0B, b1B_;
    const unsigned short* pa = u0 + (size_t)i0A * ldu + k0;
    const unsigned short* pb = u1 + (size_t)i1A * ldu + k0;
    const unsigned short* pc = u0 + (size_t)i0B * ldu + k0;
    const unsigned short* pd = u1 + (size_t)i1B * ldu + k0;
    a0A.u = *(const uint4*)(pa);     a1A.u = *(const uint4*)(pa + 8);
    b0A.u = *(const uint4*)(pb);     b1A_.u = *(const uint4*)(pb + 8);
    a0B.u = *(const uint4*)(pc);     a1B.u = *(const uint4*)(pc + 8);
    b0B.u = *(const uint4*)(pd);     b1B_.u = *(const uint4*)(pd + 8);
    float4 bbv[4];
    #pragma unroll
    for (int q = 0; q < 4; ++q) bbv[q] = *(const float4*)(b1 + k0 + q * 4);
    float4 wdv[4], wav[4];
    if constexpr (HASEX) {
        #pragma unroll
        for (int q = 0; q < 4; ++q) {
            wdv[q] = *(const float4*)(W1ex + k0 + q * 4);
            wav[q] = *(const float4*)(W1ex + 1024 + k0 + q * 4);
        }
    }
    float accA[NO], accB[NO];
    #pragma unroll
    for (int no = 0; no < NO; ++no) { accA[no] = 0.f; accB[no] = 0.f; }
    #pragma unroll
    for (int j = 0; j < 16; ++j) {
        const int q = j >> 2, c = j & 3;
        const float bbj = (&bbv[q].x)[c];
        float exA = 0.f, exB = 0.f;
        if constexpr (HASEX) {
            const float wdj = (&wdv[q].x)[c], waj = (&wav[q].x)[c];
            exA = dA * wdj + aA * waj;
            exB = dB * wdj + aB * waj;
        }
        const float hAv = (j < 8 ? bf2f(a0A.us[j]) : bf2f(a1A.us[j - 8]))
                        + (j < 8 ? bf2f(b0A.us[j]) : bf2f(b1A_.us[j - 8])) + bbj + exA;
        const float hBv = (j < 8 ? bf2f(a0B.us[j]) : bf2f(a1B.us[j - 8]))
                        + (j < 8 ? bf2f(b0B.us[j]) : bf2f(b1B_.us[j - 8])) + bbj + exB;
        const float rAv = fmaxf(hAv, 0.f);
        const float rBv = fmaxf(hBv, 0.f);
        const int kk = k0 + j;
        #pragma unroll
        for (int no = 0; no < NO; ++no) {
            const float wv = W2f[(size_t)kk * NO + no];
            accA[no] += rAv * wv;
            accB[no] += rBv * wv;
        }
    }
    const int oA = sord[p0];
    const int oB = has1 ? sord[p1] : 0;
    #pragma unroll
    for (int no = 0; no < NO; ++no) {
        float vA = accA[no], vB = accB[no];
        #pragma unroll
        for (int o = 32; o; o >>= 1) { vA += __shfl_down(vA, o); vB += __shfl_down(vB, o); }
        if (lane == 0) {
            out[(size_t)oA * NO + no] = vA + b2f[no];
            if (has1) out[(size_t)oB * NO + no] = vB + b2f[no];
        }
    }
}

// ---------------- host driver ----------------
extern "C" void kernel_launch(void* const* d_in, const int* in_sizes, int n_in,
                              void* d_out, int out_size, void* d_ws, size_t ws_size,
                              hipStream_t stream) {
    (void)n_in; (void)out_size; (void)ws_size;
    const float* x     = (const float*)d_in[0];
    const int*   eidx  = (const int*)d_in[1];
    const float* eattr = (const float*)d_in[2];
    const int*   iep   = (const int*)d_in[3];
    const int*   iei   = (const int*)d_in[4];
    const float* xyz   = (const float*)d_in[5];
    const float* vecd  = (const float*)d_in[6];
    const int*   a2bi  = (const int*)d_in[7];

    const int n   = in_sizes[0] / 39;
    const int E_  = in_sizes[1] / 2;
    const int EPn = in_sizes[3] / 2;
    const int EIn = in_sizes[4] / 2;
    const int EAn = in_sizes[7] / 2;
    const int Mp  = (n + 127) & ~127;
    const int MB  = (n + 127) / 128;

    const float* gatW[3]  = {(const float*)d_in[9],  (const float*)d_in[15], (const float*)d_in[21]};
    const float* gatWe[3] = {(const float*)d_in[10], (const float*)d_in[16], (const float*)d_in[22]};
    const float* gatAs[3] = {(const float*)d_in[11], (const float*)d_in[17], (const float*)d_in[23]};
    const float* gatAd[3] = {(const float*)d_in[12], (const float*)d_in[18], (const float*)d_in[24]};
    const float* gatAe[3] = {(const float*)d_in[13], (const float*)d_in[19], (const float*)d_in[25]};
    const float* gatB[3]  = {(const float*)d_in[14], (const float*)d_in[20], (const float*)d_in[26]};
    const float* gcnW = (const float*)d_in[27];
    const float* gcnB = (const float*)d_in[28];
    const float* fcnW1 = (const float*)d_in[29];
    const float* fcnB1 = (const float*)d_in[30];
    const float* fcnG  = (const float*)d_in[31];
    const float* fcnBe = (const float*)d_in[32];
    const float* fcnW2 = (const float*)d_in[33];
    const float* fcnB2 = (const float*)d_in[34];

    struct HeadP { const float *W1, *b1, *g, *be, *W2, *b2; };
    HeadP hp[4];
    for (int hh = 0; hh < 4; ++hh) {
        int base = 35 + hh * 6;
        hp[hh] = {(const float*)d_in[base], (const float*)d_in[base + 1], (const float*)d_in[base + 2],
                  (const float*)d_in[base + 3], (const float*)d_in[base + 4], (const float*)d_in[base + 5]};
    }

    char* w = (char*)d_ws;
    size_t off = 0;
    auto alloc = [&](size_t bytes) -> void* {
        void* p = w + off;
        off = (off + bytes + 255) & ~(size_t)255;
        return p;
    };
    int* indeg   = (int*)alloc((size_t)n * 4);
    int* fill    = (int*)alloc((size_t)n * 4);
    int* coff    = (int*)alloc((size_t)(n + 1) * 4);
    int* ceid    = (int*)alloc((size_t)E_ * 4);
    int* pcnt    = (int*)alloc((size_t)n * 4);
    int* pfill   = (int*)alloc((size_t)n * 4);
    int* poff    = (int*)alloc((size_t)(n + 1) * 4);
    int4* spp    = (int4*)alloc((size_t)EIn * 16);
    int* sord    = (int*)alloc((size_t)EIn * 4);
    float* lattr = (float*)alloc((size_t)n * 27 * 4);
    float* Wea   = (float*)alloc(27 * 4 * 4);
    float* a_e   = (float*)alloc((size_t)(E_ + n) * 4 * 4);
    float* a_s   = (float*)alloc((size_t)n * 4 * 4);
    float* a_d   = (float*)alloc((size_t)n * 4 * 4);
    float* part  = (float*)alloc((size_t)1024 * 2048 * 4);
    float* tmp   = (float*)alloc((size_t)32 * 2048 * 4);
    float* mv    = (float*)alloc(2048 * 4);
    float* W2f   = (float*)alloc((size_t)1024 * 256 * 4);
    float* b2f   = (float*)alloc(256 * 4);
    float* feat  = (float*)alloc((size_t)n * 551 * 4);
    unsigned short* hb   = (unsigned short*)alloc((size_t)n * 512 * 2);   // bf16 h (GAT) / hg (GCN)
    unsigned short* Ab   = (unsigned short*)alloc((size_t)Mp * 576 * 2);
    unsigned short* hidb = (unsigned short*)alloc((size_t)Mp * 1024 * 2);
    unsigned short* embb = (unsigned short*)alloc((size_t)Mp * 256 * 2);
    unsigned short* u01b = (unsigned short*)alloc((size_t)n * 2048 * 2);  // u0|u1 combined
    unsigned short* btB  = (unsigned short*)alloc((size_t)2048 * 256 * 2 > (size_t)1024 * 1024 * 2 ? (size_t)2048 * 1024 * 2 : (size_t)2048 * 1024 * 2);

    hipMemsetAsync(indeg, 0, (size_t)n * 4, stream);
    hipMemsetAsync(fill, 0, (size_t)n * 4, stream);
    hipMemsetAsync(hidb + (size_t)n * 1024, 0, (size_t)(Mp - n) * 1024 * 2, stream);
    hipMemsetAsync(embb + (size_t)n * 256, 0, (size_t)(Mp - n) * 256 * 2, stream);

    const int NCH = 32;
    auto stats_finish = [&](int M, int NB) {
        dim3 g1(8, NCH);
        k_red1<<<g1, 256, 0, stream>>>(part, tmp, NB, NCH);
        k_red2<<<4, 256, 0, stream>>>(tmp, mv, M, NCH);
    };
    auto stageA = [&](const float* src, int lds, int colofs, int K, int Kp) {
        int tot = Mp * Kp;
        k_stage_a<<<(tot + 255) / 256, 256, 0, stream>>>(src, lds, colofs, Ab, Kp, n, K, Mp);
    };
    auto convBt = [&](const float* src, int ldn, int K, int Kp, int N, int Np) {
        int tot = Np * Kp;
        k_conv_bt<<<(tot + 255) / 256, 256, 0, stream>>>(src, ldn, btB, Kp, K, N, Np);
    };
    auto bucket_pairs = [&](const int* pidx, int P, bool hasex) {
        hipMemsetAsync(pcnt, 0, (size_t)n * 4, stream);
        hipMemsetAsync(pfill, 0, (size_t)n * 4, stream);
        k_count<<<(P + 255) / 256, 256, 0, stream>>>(pidx, pcnt, P);
        k_scan<<<1, 1024, 0, stream>>>(pcnt, poff, n);
        if (hasex)
            k_pack_sorted<true><<<(P + 255) / 256, 256, 0, stream>>>(pidx, xyz, vecd, poff, pfill, spp, sord, P);
        else
            k_pack_sorted<false><<<(P + 255) / 256, 256, 0, stream>>>(pidx, xyz, vecd, poff, pfill, spp, sord, P);
    };

    const int* dsta = eidx + E_;
    k_count<<<(E_ + 255) / 256, 256, 0, stream>>>(dsta, indeg, E_);
    k_scan<<<1, 1024, 0, stream>>>(indeg, coff, n);
    k_fill<<<(E_ + 255) / 256, 256, 0, stream>>>(dsta, coff, fill, ceid, E_);
    k_copy_x<<<((n * 39) + 255) / 256, 256, 0, stream>>>(x, feat, n);
    k_loopattr<<<(n + 3) / 4, 128, 0, stream>>>(eattr, coff, ceid, lattr, n);

    const int colofs_in[3] = {0, 39, 167};
    const int fin[3] = {39, 128, 128};
    const int finp[3] = {64, 128, 128};
    for (int l = 0; l < 3; ++l) {
        k_wea<<<1, 128, 0, stream>>>(gatWe[l], gatAe[l], Wea);
        stageA(feat, 551, colofs_in[l], fin[l], finp[l]);
        convBt(gatW[l], 512, fin[l], finp[l], 512, 512);
        dim3 g(4, MB);
        gemm_mfma<1, false, false><<<g, 256, 0, stream>>>(Ab, finp[l], btB, finp[l], nullptr, hb, 512, n, 512, finp[l]);
        k_ae<<<(E_ + n + 255) / 256, 256, 0, stream>>>(eattr, lattr, Wea, a_e, E_, n);
        k_asd<<<(n * 4 + 255) / 256, 256, 0, stream>>>(hb, gatAs[l], gatAd[l], a_s, a_d, n);
        k_attn<<<n, 64, 0, stream>>>(hb, a_s, a_d, a_e, eidx, coff, ceid, gatB[l], feat, 39 + 128 * l, E_);
    }
    // GCN
    {
        stageA(feat, 551, 295, 128, 128);
        convBt(gcnW, 128, 128, 128, 128, 128);
        dim3 g(1, MB);
        gemm_mfma<1, false, false><<<g, 256, 0, stream>>>(Ab, 128, btB, 128, nullptr, hb, 128, n, 128, 128);
        k_gcn<<<n, 64, 0, stream>>>(hb, eidx, coff, ceid, indeg, gcnB, feat);
    }
    // FCN
    {
        stageA(feat, 551, 0, 551, 576);
        convBt(fcnW1, 1024, 551, 576, 1024, 1024);
        dim3 g(8, MB);
        gemm_mfma<1, true, true><<<g, 256, 0, stream>>>(Ab, 576, btB, 576, fcnB1, hidb, 1024, n, 1024, 576);
        k_stats1b<<<256, 256, 0, stream>>>(hidb, n, part);
        stats_finish(n, 256);
        k_fold<<<256, 256, 0, stream>>>(fcnW2, fcnG, fcnBe, fcnB2, mv, W2f, b2f, 256);
        convBt(W2f, 256, 1024, 1024, 256, 256);
        dim3 g2(2, MB);
        gemm_mfma<1, true, true><<<g2, 256, 0, stream>>>(hidb, 1024, btB, 1024, b2f, embb, 256, n, 256, 1024);
    }

    float* out = (float*)d_out;
    float* out_link = out;
    float* out_a2b  = out + (size_t)EIn;
    float* out_node = out_a2b + (size_t)EAn * 6;
    float* out_int  = out_node + (size_t)n * 16;

    const dim3 gu2(16, MB);   // combined u0|u1 GEMM: [n,256]@[256,2048]

    // ---- link head (NO=1, has d,a extras) ----
    {
        k_conv_bt2<<<(2048 * 256 + 255) / 256, 256, 0, stream>>>(hp[0].W1, btB);
        gemm_mfma<1, false, false><<<gu2, 256, 0, stream>>>(embb, 256, btB, 256, nullptr, u01b, 2048, n, 2048, 256);
        const float* W1ex = hp[0].W1 + (size_t)512 * 1024;
        bucket_pairs(iei, EIn, true);
        k_pairA<true><<<1024, 256, 0, stream>>>(u01b, u01b + 1024, 2048, hp[0].b1, W1ex, spp, EIn, part);
        stats_finish(EIn, 1024);
        k_fold<<<1, 256, 0, stream>>>(hp[0].W2, hp[0].g, hp[0].be, hp[0].b2, mv, W2f, b2f, 1);
        k_pairB<1, true><<<(EIn + 7) / 8, 256, 0, stream>>>(u01b, u01b + 1024, 2048, hp[0].b1, W1ex, W2f, b2f, spp, sord, out_link, EIn);
    }
    // ---- a2b head (NO=6, no extras) ----
    {
        k_conv_bt2<<<(2048 * 256 + 255) / 256, 256, 0, stream>>>(hp[1].W1, btB);
        gemm_mfma<1, false, false><<<gu2, 256, 0, stream>>>(embb, 256, btB, 256, nullptr, u01b, 2048, n, 2048, 256);
        bucket_pairs(a2bi, EAn, false);
        k_pairA<false><<<1024, 256, 0, stream>>>(u01b, u01b + 1024, 2048, hp[1].b1, nullptr, spp, EAn, part);
        stats_finish(EAn, 1024);
        k_fold<<<6, 256, 0, stream>>>(hp[1].W2, hp[1].g, hp[1].be, hp[1].b2, mv, W2f, b2f, 6);
        k_pairB<6, false><<<(EAn + 7) / 8, 256, 0, stream>>>(u01b, u01b + 1024, 2048, hp[1].b1, nullptr, W2f, b2f, spp, sord, out_a2b, EAn);
    }
    // ---- node head (NO=16) ----
    {
        convBt(hp[2].W1, 1024, 256, 256, 1024, 1024);
        dim3 gu(8, MB);
        gemm_mfma<1, true, true><<<gu, 256, 0, stream>>>(embb, 256, btB, 256, hp[2].b1, hidb, 1024, n, 1024, 256);
        k_stats1b<<<256, 256, 0, stream>>>(hidb, n, part);
        stats_finish(n, 256);
        k_fold<<<16, 256, 0, stream>>>(hp[2].W2, hp[2].g, hp[2].be, hp[2].b2, mv, W2f, b2f, 16);
        convBt(W2f, 16, 1024, 1024, 16, 128);
        dim3 g2(1, MB);
        gemm_mfma<0, false, true><<<g2, 256, 0, stream>>>(hidb, 1024, btB, 1024, b2f, out_node, 16, n, 16, 1024);
    }
    // ---- int head (NO=3, has d,a extras) ----
    {
        k_conv_bt2<<<(2048 * 256 + 255) / 256, 256, 0, stream>>>(hp[3].W1, btB);
        gemm_mfma<1, false, false><<<gu2, 256, 0, stream>>>(embb, 256, btB, 256, nullptr, u01b, 2048, n, 2048, 256);
        const float* W1ex = hp[3].W1 + (size_t)512 * 1024;
        bucket_pairs(iep, EPn, true);
        k_pairA<true><<<1024, 256, 0, stream>>>(u01b, u01b + 1024, 2048, hp[3].b1, W1ex, spp, EPn, part);
        stats_finish(EPn, 1024);
        k_fold<<<3, 256, 0, stream>>>(hp[3].W2, hp[3].g, hp[3].be, hp[3].b2, mv, W2f, b2f, 3);
        k_pairB<3, true><<<(EPn + 7) / 8, 256, 0, stream>>>(u01b, u01b + 1024, 2048, hp[3].b1, W1ex, W2f, b2f, spp, sord, out_int, EPn);
    }
}